// Round 6
// baseline (308.226 us; speedup 1.0000x reference)
//
#include <hip/hip_runtime.h>
#include <hip/hip_bf16.h>
#include <math.h>

namespace {

constexpr int B  = 4;
constexpr int N  = 2048;
constexpr int F0 = 6;
constexpr int F  = 64;
constexpr int DK = 16;
constexpr float EPS = 1e-5f;
constexpr int NCH0 = 16;  // n-chunks, layer-0 adjacency
constexpr int MT   = N / 64;  // m-tiles for big layers

typedef float fx4 __attribute__((ext_vector_type(4)));  // native vec for nontemporal builtins

// ---------------- squared norms per node ----------------
template<int D>
__global__ __launch_bounds__(256) void k_sqnorm(const float* __restrict__ x,
                                                float* __restrict__ sqn) {
  int idx = blockIdx.x * 256 + threadIdx.x;
  if (idx >= B * N) return;
  int b = idx >> 11;
  int n = idx & (N - 1);
  const float* xp = x + (size_t)b * D * N + n;
  float s = 0.f;
#pragma unroll
  for (int d = 0; d < D; ++d) { float v = xp[(size_t)d * N]; s = fmaf(v, v, s); }
  sqn[idx] = s;
}

// ---------------- layer-0 fused adjacency + deg + adj_msg (D=F=6) ----------------
__global__ __launch_bounds__(256) void k_adj0(const float* __restrict__ x,
                                              const float* __restrict__ sqn,
                                              const float* __restrict__ sigma,
                                              float* __restrict__ pdmsg,  // (NCH0,B,F0,N)
                                              float* __restrict__ pdeg) { // (NCH0,B,N)
  constexpr int NC = N / NCH0;  // 128
  int t = threadIdx.x;
  int m = blockIdx.x * 256 + t;
  int ch = blockIdx.y, b = blockIdx.z;
  float sg = sigma[0];
  float inv_s2 = 1.f / (sg * sg);
  const float* xb = x + (size_t)b * F0 * N;
  float pm[F0];
#pragma unroll
  for (int d = 0; d < F0; ++d) pm[d] = xb[(size_t)d * N + m];
  float sqm = sqn[b * N + m];
  float acc[F0] = {};
  float deg = 0.f;
  // [nn][d0..5, 6=sqnorm, 7 pad] -> per-nn reads are two broadcast b128
  __shared__ __align__(16) float xt[64][8];
  int n0 = ch * NC;
  for (int nt = 0; nt < NC; nt += 64) {
    __syncthreads();
    for (int e = t; e < F0 * 64; e += 256) {
      int d = e >> 6, nn = e & 63;
      xt[nn][d] = xb[(size_t)d * N + n0 + nt + nn];
    }
    if (t < 64) xt[t][6] = sqn[b * N + n0 + nt + t];
    __syncthreads();
#pragma unroll 2
    for (int nn = 0; nn < 64; ++nn) {
      float4 p0 = *(const float4*)&xt[nn][0];
      float4 p1 = *(const float4*)&xt[nn][4];
      float g = fmaf(pm[0], p0.x, 0.f);
      g = fmaf(pm[1], p0.y, g);
      g = fmaf(pm[2], p0.z, g);
      g = fmaf(pm[3], p0.w, g);
      g = fmaf(pm[4], p1.x, g);
      g = fmaf(pm[5], p1.y, g);
      float dist = fmaxf(sqm + p1.z - 2.f * g, 0.f);
      float a = __expf(-dist * inv_s2);
      deg += a;
      acc[0] = fmaf(a, p0.x, acc[0]);
      acc[1] = fmaf(a, p0.y, acc[1]);
      acc[2] = fmaf(a, p0.z, acc[2]);
      acc[3] = fmaf(a, p0.w, acc[3]);
      acc[4] = fmaf(a, p1.x, acc[4]);
      acc[5] = fmaf(a, p1.y, acc[5]);
    }
  }
  size_t base = (size_t)ch * B + b;
#pragma unroll
  for (int d = 0; d < F0; ++d) pdmsg[(base * F0 + d) * N + m] = acc[d];
  pdeg[base * N + m] = deg;
}

// ---------------- big-layer fused adjacency + deg + adj_msg (D=16, F=64) ----------------
// XCD-aware swizzle + NON-TEMPORAL partial stores (the 67MB pdmsg stream was
// evicting the 2.5MB V/proj read set from L2 -> 133MB refetch in R4).
__global__ __launch_bounds__(256, 3) void k_adjmsg(const float* __restrict__ proj,
                                                   const float* __restrict__ sqn,
                                                   const float* __restrict__ V,
                                                   float* __restrict__ pdmsg,  // (nch,B,F,N)
                                                   float* __restrict__ pdeg,   // (nch,B,N)
                                                   int nch, int cpx) {         // cpx = nch*B/8
  constexpr int D = DK;
  const int NCb = N / nch;
  int i = blockIdx.x;
  int xcd = i & 7;            // dispatch round-robins XCDs
  int j = i >> 3;
  int lc = j / MT;
  int mtile = j - lc * MT;
  int combo = xcd * cpx + lc; // 0..nch*B-1, bijective
  int ch = combo >> 2;        // /B
  int b  = combo & 3;
  int M0 = mtile * 64;
  int n0 = ch * NCb;

  int t = threadIdx.x;
  int tm = t & 15, tf = t >> 4;
  int m4 = tm * 4, f4 = tf * 4, n4 = tf * 4;
  const float* pb = proj + (size_t)b * D * N;
  const float* vb = V + (size_t)b * F * N;
  const float* sq = sqn + (size_t)b * N;

  __shared__ __align__(16) float pnS[D][64];
  __shared__ float sqnS[64];
  __shared__ __align__(16) float adjS[64][68];  // 68: b128-aligned rows, 2-way banks max
  __shared__ __align__(16) float vS[64][68];    // f-major: [f][n], coalesced staging
  __shared__ float degW[4][64];

  // m-tile operand in registers (float4 array, fully unrolled access -> SROA)
  float4 pmr[D];
#pragma unroll
  for (int d = 0; d < D; ++d)
    pmr[d] = *(const float4*)&pb[(size_t)d * N + M0 + m4];
  float4 sqm4 = *(const float4*)&sq[M0 + m4];
  float sqmr[4] = {sqm4.x, sqm4.y, sqm4.z, sqm4.w};

  float acc[4][4] = {};
  float pd[4] = {};

  for (int nt = 0; nt < NCb; nt += 64) {
    __syncthreads();
    {  // stage proj n-tile (256 float4, one per thread)
      int d = t >> 4, nq = (t & 15) * 4;
      *(float4*)&pnS[d][nq] = *(const float4*)&pb[(size_t)d * N + n0 + nt + nq];
    }
    if (t < 64) sqnS[t] = sq[n0 + nt + t];
#pragma unroll
    for (int r = 0; r < 4; ++r) {  // stage V f-major (coalesced, conflict-free)
      int e = r * 256 + t;
      int f = e >> 4, nq = (e & 15) * 4;
      *(float4*)&vS[f][nq] = *(const float4*)&vb[(size_t)f * N + n0 + nt + nq];
    }
    __syncthreads();
    // gram 4x4 + exp -> adj tile
    float g[4][4] = {};
#pragma unroll
    for (int d = 0; d < D; ++d) {
      float4 bn4 = *(const float4*)&pnS[d][n4];
      float bk[4] = {bn4.x, bn4.y, bn4.z, bn4.w};
      float pj[4] = {pmr[d].x, pmr[d].y, pmr[d].z, pmr[d].w};
#pragma unroll
      for (int jj = 0; jj < 4; ++jj)
#pragma unroll
        for (int k = 0; k < 4; ++k) g[jj][k] = fmaf(pj[jj], bk[k], g[jj][k]);
    }
#pragma unroll
    for (int k = 0; k < 4; ++k) {
      float row[4];
#pragma unroll
      for (int jj = 0; jj < 4; ++jj) {
        float dist = fmaxf(sqmr[jj] + sqnS[n4 + k] - 2.f * g[jj][k], 0.f);
        float a = __expf(-dist);
        row[jj] = a;
        pd[jj] += a;
      }
      *(float4*)&adjS[n4 + k][m4] = *(float4*)row;
    }
    __syncthreads();
    // PV: acc[i][j] += sum_n V[f4+i][n] * adj[n][m4+j]; 8 aligned b128 per 64 FMA
#pragma unroll
    for (int nn = 0; nn < 64; nn += 4) {
      float4 ar[4], vr[4];
#pragma unroll
      for (int r = 0; r < 4; ++r) ar[r] = *(const float4*)&adjS[nn + r][m4];
#pragma unroll
      for (int ii = 0; ii < 4; ++ii) vr[ii] = *(const float4*)&vS[f4 + ii][nn];
#pragma unroll
      for (int ii = 0; ii < 4; ++ii) {
        float vi[4] = {vr[ii].x, vr[ii].y, vr[ii].z, vr[ii].w};
#pragma unroll
        for (int r = 0; r < 4; ++r) {
          float aj[4] = {ar[r].x, ar[r].y, ar[r].z, ar[r].w};
#pragma unroll
          for (int jj = 0; jj < 4; ++jj)
            acc[ii][jj] = fmaf(vi[r], aj[jj], acc[ii][jj]);
        }
      }
    }
  }
  // deg: butterfly over same-tm lanes in wave, then cross-wave via LDS
#pragma unroll
  for (int jj = 0; jj < 4; ++jj) {
    pd[jj] += __shfl_xor(pd[jj], 16);
    pd[jj] += __shfl_xor(pd[jj], 32);
  }
  if ((t & 63) < 16) {
#pragma unroll
    for (int jj = 0; jj < 4; ++jj) degW[t >> 6][m4 + jj] = pd[jj];
  }
  __syncthreads();
  if (t < 64) {
    float s = degW[0][t] + degW[1][t] + degW[2][t] + degW[3][t];
    __builtin_nontemporal_store(s, &pdeg[((size_t)combo) * N + M0 + t]);
  }
  float* pdm = pdmsg + (size_t)combo * F * N;
#pragma unroll
  for (int i2 = 0; i2 < 4; ++i2) {
    fx4 o4 = {acc[i2][0], acc[i2][1], acc[i2][2], acc[i2][3]};
    __builtin_nontemporal_store(o4, (fx4*)&pdm[(size_t)(f4 + i2) * N + M0 + m4]);
  }
}

// ---------------- chunk-combine + gopconv epilogue (compile-time NCHt!) ----------------
template<int FIN, int NCHt>
__global__ __launch_bounds__(256) void k_gopconv(const float* __restrict__ X,
                                                 const float* __restrict__ pdmsg,
                                                 const float* __restrict__ pdeg,
                                                 const float* __restrict__ W,     // (64,2*FIN)
                                                 const float* __restrict__ bias,  // (64)
                                                 const float* __restrict__ Wres,  // (64,FIN)
                                                 const float* __restrict__ bres,  // (64)
                                                 float* __restrict__ out) {       // (B,64,N)
  int t = threadIdx.x;
  int m = blockIdx.x * 64 + (t & 63);
  int og = __builtin_amdgcn_readfirstlane(t >> 6);  // wave-uniform -> scalar W loads
  int b = blockIdx.y;
  float deg = 0.f;
#pragma unroll
  for (int c = 0; c < NCHt; ++c)
    deg += __builtin_nontemporal_load(&pdeg[((size_t)c * B + b) * N + m]);
  float cacc[16], racc[16];
#pragma unroll
  for (int k = 0; k < 16; ++k) {
    cacc[k] = bias[og * 16 + k];
    racc[k] = bres[og * 16 + k];
  }
#pragma unroll 4
  for (int f = 0; f < FIN; ++f) {
    float x = X[((size_t)b * FIN + f) * N + m];
    float dm = 0.f;
#pragma unroll
    for (int c = 0; c < NCHt; ++c)
      dm += __builtin_nontemporal_load(&pdmsg[(((size_t)c * B + b) * FIN + f) * N + m]);
    float c0 = x * deg;
#pragma unroll
    for (int k = 0; k < 16; ++k) {
      int o = og * 16 + k;
      cacc[k] = fmaf(W[(size_t)o * 2 * FIN + f], c0, cacc[k]);
      cacc[k] = fmaf(W[(size_t)o * 2 * FIN + FIN + f], dm, cacc[k]);
      racc[k] = fmaf(Wres[(size_t)o * FIN + f], x, racc[k]);
    }
  }
#pragma unroll
  for (int k = 0; k < 16; ++k) {
    out[((size_t)b * F + og * 16 + k) * N + m] = fmaxf(cacc[k], 0.f) + racc[k];
  }
}

// ---------------- fused spatialnorm: stats + normalize, one block per (b,f) row ----------------
__global__ __launch_bounds__(256) void k_norm(const float* __restrict__ emb,
                                              float* __restrict__ Vout) {
  int row = blockIdx.x;  // b*F + f
  int t = threadIdx.x;
  const float4* p = (const float4*)(emb + (size_t)row * N);
  float4* o = (float4*)(Vout + (size_t)row * N);
  __shared__ __align__(16) float4 buf[N / 4];  // 8KB
  float s = 0.f, s2 = 0.f;
#pragma unroll
  for (int i = t; i < N / 4; i += 256) {
    float4 v = p[i];
    buf[i] = v;
    s += v.x + v.y + v.z + v.w;
    s2 = fmaf(v.x, v.x, s2); s2 = fmaf(v.y, v.y, s2);
    s2 = fmaf(v.z, v.z, s2); s2 = fmaf(v.w, v.w, s2);
  }
#pragma unroll
  for (int off = 1; off < 64; off <<= 1) {
    s += __shfl_xor(s, off);
    s2 += __shfl_xor(s2, off);
  }
  __shared__ float rs[4], rq[4], stat[2];
  if ((t & 63) == 0) { rs[t >> 6] = s; rq[t >> 6] = s2; }
  __syncthreads();
  if (t == 0) {
    float S = rs[0] + rs[1] + rs[2] + rs[3];
    float Q = rq[0] + rq[1] + rq[2] + rq[3];
    float mn = S / N;
    float var = Q / N - mn * mn;
    stat[0] = mn;
    stat[1] = rsqrtf(var + EPS);
  }
  __syncthreads();
  float mn = stat[0], r = stat[1];
#pragma unroll
  for (int i = t; i < N / 4; i += 256) {
    float4 v = buf[i];
    o[i] = make_float4((v.x - mn) * r, (v.y - mn) * r, (v.z - mn) * r, (v.w - mn) * r);
  }
}

// ---------------- fused proj = adj_proj[i] @ emb  +  sqnorm(proj) ----------------
__global__ __launch_bounds__(256) void k_proj_sq(const float* __restrict__ ap,   // (DK,F)
                                                 const float* __restrict__ emb,  // (B,F,N)
                                                 float* __restrict__ proj,       // (B,DK,N)
                                                 float* __restrict__ sqn) {      // (B,N)
  int t = threadIdx.x;
  int b = blockIdx.y;
  int n = blockIdx.x * 64 + (t & 63);
  int dg = __builtin_amdgcn_readfirstlane(t >> 6);  // wave-uniform d-group
  const float* e = emb + (size_t)b * F * N + n;
  float acc[4] = {0.f, 0.f, 0.f, 0.f};
#pragma unroll 4
  for (int f = 0; f < F; ++f) {
    float x = e[(size_t)f * N];
#pragma unroll
    for (int q = 0; q < 4; ++q) acc[q] = fmaf(ap[(dg * 4 + q) * F + f], x, acc[q]);
  }
  float s = 0.f;
#pragma unroll
  for (int q = 0; q < 4; ++q) {
    proj[((size_t)b * DK + dg * 4 + q) * N + n] = acc[q];
    s = fmaf(acc[q], acc[q], s);
  }
  __shared__ float sp[4][64];
  sp[dg][t & 63] = s;
  __syncthreads();
  if (t < 64) sqn[(size_t)b * N + blockIdx.x * 64 + t] =
      sp[0][t] + sp[1][t] + sp[2][t] + sp[3][t];
}

// ---------------- readout: pool + instance-norm + fcl + sigmoid ----------------
__global__ __launch_bounds__(256) void k_readout(const float* __restrict__ emb,
                                                 const float* __restrict__ fw,
                                                 const float* __restrict__ fb,
                                                 float* __restrict__ out) {
  int b = blockIdx.x, t = threadIdx.x;
  int f = t & 63, part = t >> 6;
  const float* p = emb + ((size_t)b * F + f) * N;
  float s = 0.f;
  for (int i = part * (N / 4); i < (part + 1) * (N / 4); ++i) s += p[i];
  __shared__ float red[4][64];
  red[part][f] = s;
  __syncthreads();
  if (t == 0) {
    float pooled[64];
    float mn = 0.f;
    for (int q = 0; q < 64; ++q) {
      float po = (red[0][q] + red[1][q] + red[2][q] + red[3][q]) / (float)N;
      pooled[q] = po;
      mn += po;
    }
    mn /= 64.f;
    float var = 0.f;
    for (int q = 0; q < 64; ++q) {
      float d2 = pooled[q] - mn;
      var = fmaf(d2, d2, var);
    }
    var /= 64.f;
    float r = rsqrtf(var + EPS);
    float lg = fb[0];
    for (int q = 0; q < 64; ++q) lg = fmaf((pooled[q] - mn) * r, fw[q], lg);
    out[b] = 1.f / (1.f + __expf(-lg));
  }
}

}  // namespace

extern "C" void kernel_launch(void* const* d_in, const int* in_sizes, int n_in,
                              void* d_out, int out_size, void* d_ws, size_t ws_size,
                              hipStream_t stream) {
  const float* emb_in   = (const float*)d_in[0];
  const float* sigma    = (const float*)d_in[1];
  const float* fst_w    = (const float*)d_in[2];
  const float* fst_b    = (const float*)d_in[3];
  const float* fst_wres = (const float*)d_in[4];
  const float* fst_bres = (const float*)d_in[5];
  const float* adj_proj = (const float*)d_in[6];
  const float* w        = (const float*)d_in[7];
  const float* bw       = (const float*)d_in[8];
  const float* wres     = (const float*)d_in[9];
  const float* bres     = (const float*)d_in[10];
  const float* fcl_w    = (const float*)d_in[11];
  const float* fcl_b    = (const float*)d_in[12];

  // runtime chunk count for big layers, gated on workspace size
  auto need_bytes = [](int nch) -> size_t {
    size_t f = 0;
    f += B * N;                                        // sqn
    f += (size_t)((nch > NCH0) ? nch : NCH0) * B * N;  // pdeg
    size_t pd1 = (size_t)nch * B * F * N, pd0 = (size_t)NCH0 * B * F0 * N;
    f += (pd1 > pd0) ? pd1 : pd0;                      // pdmsg
    f += 3 * (size_t)B * F * N;                        // embA, embB, Vb
    f += (size_t)B * DK * N;                           // projb
    return f * 4;
  };
  int nch = (ws_size >= need_bytes(8)) ? 8 : 4;
  int cpx = nch * B / 8;

  float* ws = (float*)d_ws;
  float* sqn   = ws;  ws += B * N;
  float* pdeg  = ws;  ws += (size_t)((nch > NCH0) ? nch : NCH0) * B * N;
  size_t pd1 = (size_t)nch * B * F * N, pd0 = (size_t)NCH0 * B * F0 * N;
  float* pdmsg = ws;  ws += (pd1 > pd0) ? pd1 : pd0;
  float* embA  = ws;  ws += (size_t)B * F * N;
  float* embB  = ws;  ws += (size_t)B * F * N;
  float* Vb    = ws;  ws += (size_t)B * F * N;
  float* projb = ws;  ws += (size_t)B * DK * N;

  // ---- layer 0 (input adjacency with sigma) ----
  k_sqnorm<F0><<<dim3(B * N / 256), 256, 0, stream>>>(emb_in, sqn);
  k_adj0<<<dim3(N / 256, NCH0, B), 256, 0, stream>>>(emb_in, sqn, sigma, pdmsg, pdeg);
  k_gopconv<F0, NCH0><<<dim3(N / 64, B), 256, 0, stream>>>(
      emb_in, pdmsg, pdeg, fst_w, fst_b, fst_wres, fst_bres, embA);

  // ---- layers 1..2 (learned adjacency) ----
  const float* src = embA;
  float* dst = embB;
  for (int i = 0; i < 2; ++i) {
    k_proj_sq<<<dim3(N / 64, B), 256, 0, stream>>>(adj_proj + (size_t)i * DK * F, src,
                                                   projb, sqn);
    k_norm<<<dim3(B * F), 256, 0, stream>>>(src, Vb);
    k_adjmsg<<<dim3(MT * nch * B), 256, 0, stream>>>(projb, sqn, Vb, pdmsg, pdeg, nch, cpx);
    if (nch == 8) {
      k_gopconv<F, 8><<<dim3(N / 64, B), 256, 0, stream>>>(
          Vb, pdmsg, pdeg, w + (size_t)i * F * 2 * F, bw + (size_t)i * F,
          wres + (size_t)i * F * F, bres + (size_t)i * F, dst);
    } else {
      k_gopconv<F, 4><<<dim3(N / 64, B), 256, 0, stream>>>(
          Vb, pdmsg, pdeg, w + (size_t)i * F * 2 * F, bw + (size_t)i * F,
          wres + (size_t)i * F * F, bres + (size_t)i * F, dst);
    }
    float* tmp = (float*)src;
    src = dst;
    dst = tmp;
  }

  k_readout<<<dim3(B), 256, 0, stream>>>(src, fcl_w, fcl_b, (float*)d_out);
}

// Round 7
// 234.672 us; speedup vs baseline: 1.3134x; 1.3134x over previous
//
#include <hip/hip_runtime.h>
#include <hip/hip_bf16.h>
#include <math.h>

namespace {

constexpr int B  = 4;
constexpr int N  = 2048;
constexpr int F0 = 6;
constexpr int F  = 64;
constexpr int DK = 16;
constexpr float EPS = 1e-5f;
constexpr int NCH0 = 16;  // n-chunks, layer-0 adjacency
constexpr int MT   = N / 64;  // m-tiles for big layers

typedef float fx4 __attribute__((ext_vector_type(4)));  // native vec for nontemporal builtins

// ---------------- squared norms per node ----------------
template<int D>
__global__ __launch_bounds__(256) void k_sqnorm(const float* __restrict__ x,
                                                float* __restrict__ sqn) {
  int idx = blockIdx.x * 256 + threadIdx.x;
  if (idx >= B * N) return;
  int b = idx >> 11;
  int n = idx & (N - 1);
  const float* xp = x + (size_t)b * D * N + n;
  float s = 0.f;
#pragma unroll
  for (int d = 0; d < D; ++d) { float v = xp[(size_t)d * N]; s = fmaf(v, v, s); }
  sqn[idx] = s;
}

// ---------------- layer-0 fused adjacency + deg + adj_msg (D=F=6) ----------------
__global__ __launch_bounds__(256) void k_adj0(const float* __restrict__ x,
                                              const float* __restrict__ sqn,
                                              const float* __restrict__ sigma,
                                              float* __restrict__ pdmsg,  // (NCH0,B,F0,N)
                                              float* __restrict__ pdeg) { // (NCH0,B,N)
  constexpr int NC = N / NCH0;  // 128
  int t = threadIdx.x;
  int m = blockIdx.x * 256 + t;
  int ch = blockIdx.y, b = blockIdx.z;
  float sg = sigma[0];
  float inv_s2 = 1.f / (sg * sg);
  const float* xb = x + (size_t)b * F0 * N;
  float pm[F0];
#pragma unroll
  for (int d = 0; d < F0; ++d) pm[d] = xb[(size_t)d * N + m];
  float sqm = sqn[b * N + m];
  float acc[F0] = {};
  float deg = 0.f;
  // [nn][d0..5, 6=sqnorm, 7 pad] -> per-nn reads are two broadcast b128
  __shared__ __align__(16) float xt[64][8];
  int n0 = ch * NC;
  for (int nt = 0; nt < NC; nt += 64) {
    __syncthreads();
    for (int e = t; e < F0 * 64; e += 256) {
      int d = e >> 6, nn = e & 63;
      xt[nn][d] = xb[(size_t)d * N + n0 + nt + nn];
    }
    if (t < 64) xt[t][6] = sqn[b * N + n0 + nt + t];
    __syncthreads();
#pragma unroll 2
    for (int nn = 0; nn < 64; ++nn) {
      float4 p0 = *(const float4*)&xt[nn][0];
      float4 p1 = *(const float4*)&xt[nn][4];
      float g = fmaf(pm[0], p0.x, 0.f);
      g = fmaf(pm[1], p0.y, g);
      g = fmaf(pm[2], p0.z, g);
      g = fmaf(pm[3], p0.w, g);
      g = fmaf(pm[4], p1.x, g);
      g = fmaf(pm[5], p1.y, g);
      float dist = fmaxf(sqm + p1.z - 2.f * g, 0.f);
      float a = __expf(-dist * inv_s2);
      deg += a;
      acc[0] = fmaf(a, p0.x, acc[0]);
      acc[1] = fmaf(a, p0.y, acc[1]);
      acc[2] = fmaf(a, p0.z, acc[2]);
      acc[3] = fmaf(a, p0.w, acc[3]);
      acc[4] = fmaf(a, p1.x, acc[4]);
      acc[5] = fmaf(a, p1.y, acc[5]);
    }
  }
  size_t base = (size_t)ch * B + b;
#pragma unroll
  for (int d = 0; d < F0; ++d) pdmsg[(base * F0 + d) * N + m] = acc[d];
  pdeg[base * N + m] = deg;
}

// ---------------- big-layer fused adjacency + deg + adj_msg (D=16, F=64) ----------------
// XCD-aware swizzle + NON-TEMPORAL partial stores (keep the 67MB pdmsg stream
// out of L2 so the 2.5MB V/proj read set stays resident).
__global__ __launch_bounds__(256, 3) void k_adjmsg(const float* __restrict__ proj,
                                                   const float* __restrict__ sqn,
                                                   const float* __restrict__ V,
                                                   float* __restrict__ pdmsg,  // (nch,B,F,N)
                                                   float* __restrict__ pdeg,   // (nch,B,N)
                                                   int nch, int cpx) {         // cpx = nch*B/8
  constexpr int D = DK;
  const int NCb = N / nch;
  int i = blockIdx.x;
  int xcd = i & 7;            // dispatch round-robins XCDs
  int j = i >> 3;
  int lc = j / MT;
  int mtile = j - lc * MT;
  int combo = xcd * cpx + lc; // 0..nch*B-1, bijective
  int ch = combo >> 2;        // /B
  int b  = combo & 3;
  int M0 = mtile * 64;
  int n0 = ch * NCb;

  int t = threadIdx.x;
  int tm = t & 15, tf = t >> 4;
  int m4 = tm * 4, f4 = tf * 4, n4 = tf * 4;
  const float* pb = proj + (size_t)b * D * N;
  const float* vb = V + (size_t)b * F * N;
  const float* sq = sqn + (size_t)b * N;

  __shared__ __align__(16) float pnS[D][64];
  __shared__ float sqnS[64];
  __shared__ __align__(16) float adjS[64][68];  // 68: b128-aligned rows, 2-way banks max
  __shared__ __align__(16) float vS[64][68];    // f-major: [f][n], coalesced staging
  __shared__ float degW[4][64];

  // m-tile operand in registers (float4 array, fully unrolled access -> SROA)
  float4 pmr[D];
#pragma unroll
  for (int d = 0; d < D; ++d)
    pmr[d] = *(const float4*)&pb[(size_t)d * N + M0 + m4];
  float4 sqm4 = *(const float4*)&sq[M0 + m4];
  float sqmr[4] = {sqm4.x, sqm4.y, sqm4.z, sqm4.w};

  float acc[4][4] = {};
  float pd[4] = {};

  for (int nt = 0; nt < NCb; nt += 64) {
    __syncthreads();
    {  // stage proj n-tile (256 float4, one per thread)
      int d = t >> 4, nq = (t & 15) * 4;
      *(float4*)&pnS[d][nq] = *(const float4*)&pb[(size_t)d * N + n0 + nt + nq];
    }
    if (t < 64) sqnS[t] = sq[n0 + nt + t];
#pragma unroll
    for (int r = 0; r < 4; ++r) {  // stage V f-major (coalesced, conflict-free)
      int e = r * 256 + t;
      int f = e >> 4, nq = (e & 15) * 4;
      *(float4*)&vS[f][nq] = *(const float4*)&vb[(size_t)f * N + n0 + nt + nq];
    }
    __syncthreads();
    // gram 4x4 + exp -> adj tile
    float g[4][4] = {};
#pragma unroll
    for (int d = 0; d < D; ++d) {
      float4 bn4 = *(const float4*)&pnS[d][n4];
      float bk[4] = {bn4.x, bn4.y, bn4.z, bn4.w};
      float pj[4] = {pmr[d].x, pmr[d].y, pmr[d].z, pmr[d].w};
#pragma unroll
      for (int jj = 0; jj < 4; ++jj)
#pragma unroll
        for (int k = 0; k < 4; ++k) g[jj][k] = fmaf(pj[jj], bk[k], g[jj][k]);
    }
#pragma unroll
    for (int k = 0; k < 4; ++k) {
      float row[4];
#pragma unroll
      for (int jj = 0; jj < 4; ++jj) {
        float dist = fmaxf(sqmr[jj] + sqnS[n4 + k] - 2.f * g[jj][k], 0.f);
        float a = __expf(-dist);
        row[jj] = a;
        pd[jj] += a;
      }
      *(float4*)&adjS[n4 + k][m4] = *(float4*)row;
    }
    __syncthreads();
    // PV: acc[i][j] += sum_n V[f4+i][n] * adj[n][m4+j]; 8 aligned b128 per 64 FMA
#pragma unroll
    for (int nn = 0; nn < 64; nn += 4) {
      float4 ar[4], vr[4];
#pragma unroll
      for (int r = 0; r < 4; ++r) ar[r] = *(const float4*)&adjS[nn + r][m4];
#pragma unroll
      for (int ii = 0; ii < 4; ++ii) vr[ii] = *(const float4*)&vS[f4 + ii][nn];
#pragma unroll
      for (int ii = 0; ii < 4; ++ii) {
        float vi[4] = {vr[ii].x, vr[ii].y, vr[ii].z, vr[ii].w};
#pragma unroll
        for (int r = 0; r < 4; ++r) {
          float aj[4] = {ar[r].x, ar[r].y, ar[r].z, ar[r].w};
#pragma unroll
          for (int jj = 0; jj < 4; ++jj)
            acc[ii][jj] = fmaf(vi[r], aj[jj], acc[ii][jj]);
        }
      }
    }
  }
  // deg: butterfly over same-tm lanes in wave, then cross-wave via LDS
#pragma unroll
  for (int jj = 0; jj < 4; ++jj) {
    pd[jj] += __shfl_xor(pd[jj], 16);
    pd[jj] += __shfl_xor(pd[jj], 32);
  }
  if ((t & 63) < 16) {
#pragma unroll
    for (int jj = 0; jj < 4; ++jj) degW[t >> 6][m4 + jj] = pd[jj];
  }
  __syncthreads();
  if (t < 64) {
    float s = degW[0][t] + degW[1][t] + degW[2][t] + degW[3][t];
    __builtin_nontemporal_store(s, &pdeg[((size_t)combo) * N + M0 + t]);
  }
  float* pdm = pdmsg + (size_t)combo * F * N;
#pragma unroll
  for (int i2 = 0; i2 < 4; ++i2) {
    fx4 o4 = {acc[i2][0], acc[i2][1], acc[i2][2], acc[i2][3]};
    __builtin_nontemporal_store(o4, (fx4*)&pdm[(size_t)(f4 + i2) * N + M0 + m4]);
  }
}

// ---------------- in-place chunk reduce: chunk 0 += chunks 1..CH-1 ----------------
// Massive-parallel pure-BW kernel; NT reads (stream), regular store (L2-resident
// for the following gopconv).
template<int CH, int FF>
__global__ __launch_bounds__(256) void k_combine(float* __restrict__ pdmsg,
                                                 float* __restrict__ pdeg) {
  constexpr int E1 = B * FF * N / 4;  // dmsg float4 count
  constexpr int E2 = B * N / 4;       // deg float4 count
  int idx = blockIdx.x * 256 + threadIdx.x;
  if (idx < E1) {
    fx4* p = (fx4*)pdmsg;
    fx4 s = __builtin_nontemporal_load(&p[idx]);
#pragma unroll
    for (int c = 1; c < CH; ++c) s += __builtin_nontemporal_load(&p[(size_t)c * E1 + idx]);
    p[idx] = s;
  } else if (idx < E1 + E2) {
    int j2 = idx - E1;
    fx4* p = (fx4*)pdeg;
    fx4 s = __builtin_nontemporal_load(&p[j2]);
#pragma unroll
    for (int c = 1; c < CH; ++c) s += __builtin_nontemporal_load(&p[(size_t)c * E2 + j2]);
    p[j2] = s;
  }
}

// ---------------- gopconv epilogue on COMBINED dmsg/deg ----------------
template<int FIN>
__global__ __launch_bounds__(256) void k_gopconv(const float* __restrict__ X,
                                                 const float* __restrict__ dmsg,  // (B,FIN,N)
                                                 const float* __restrict__ deg,   // (B,N)
                                                 const float* __restrict__ W,     // (64,2*FIN)
                                                 const float* __restrict__ bias,  // (64)
                                                 const float* __restrict__ Wres,  // (64,FIN)
                                                 const float* __restrict__ bres,  // (64)
                                                 float* __restrict__ out) {       // (B,64,N)
  int t = threadIdx.x;
  int m = blockIdx.x * 64 + (t & 63);
  int og = __builtin_amdgcn_readfirstlane(t >> 6);  // wave-uniform -> scalar W loads
  int b = blockIdx.y;
  float dg = deg[(size_t)b * N + m];
  float cacc[16], racc[16];
#pragma unroll
  for (int k = 0; k < 16; ++k) {
    cacc[k] = bias[og * 16 + k];
    racc[k] = bres[og * 16 + k];
  }
#pragma unroll 2
  for (int f = 0; f < FIN; ++f) {
    float x = X[((size_t)b * FIN + f) * N + m];
    float dm = dmsg[((size_t)b * FIN + f) * N + m];
    float c0 = x * dg;
#pragma unroll
    for (int k = 0; k < 16; ++k) {
      int o = og * 16 + k;
      cacc[k] = fmaf(W[(size_t)o * 2 * FIN + f], c0, cacc[k]);
      cacc[k] = fmaf(W[(size_t)o * 2 * FIN + FIN + f], dm, cacc[k]);
      racc[k] = fmaf(Wres[(size_t)o * FIN + f], x, racc[k]);
    }
  }
#pragma unroll
  for (int k = 0; k < 16; ++k) {
    out[((size_t)b * F + og * 16 + k) * N + m] = fmaxf(cacc[k], 0.f) + racc[k];
  }
}

// ---------------- fused spatialnorm: stats + normalize, one block per (b,f) row ----------------
__global__ __launch_bounds__(256) void k_norm(const float* __restrict__ emb,
                                              float* __restrict__ Vout) {
  int row = blockIdx.x;  // b*F + f
  int t = threadIdx.x;
  const float4* p = (const float4*)(emb + (size_t)row * N);
  float4* o = (float4*)(Vout + (size_t)row * N);
  __shared__ __align__(16) float4 buf[N / 4];  // 8KB
  float s = 0.f, s2 = 0.f;
#pragma unroll
  for (int i = t; i < N / 4; i += 256) {
    float4 v = p[i];
    buf[i] = v;
    s += v.x + v.y + v.z + v.w;
    s2 = fmaf(v.x, v.x, s2); s2 = fmaf(v.y, v.y, s2);
    s2 = fmaf(v.z, v.z, s2); s2 = fmaf(v.w, v.w, s2);
  }
#pragma unroll
  for (int off = 1; off < 64; off <<= 1) {
    s += __shfl_xor(s, off);
    s2 += __shfl_xor(s2, off);
  }
  __shared__ float rs[4], rq[4], stat[2];
  if ((t & 63) == 0) { rs[t >> 6] = s; rq[t >> 6] = s2; }
  __syncthreads();
  if (t == 0) {
    float S = rs[0] + rs[1] + rs[2] + rs[3];
    float Q = rq[0] + rq[1] + rq[2] + rq[3];
    float mn = S / N;
    float var = Q / N - mn * mn;
    stat[0] = mn;
    stat[1] = rsqrtf(var + EPS);
  }
  __syncthreads();
  float mn = stat[0], r = stat[1];
#pragma unroll
  for (int i = t; i < N / 4; i += 256) {
    float4 v = buf[i];
    o[i] = make_float4((v.x - mn) * r, (v.y - mn) * r, (v.z - mn) * r, (v.w - mn) * r);
  }
}

// ---------------- fused proj = adj_proj[i] @ emb  +  sqnorm(proj) ----------------
__global__ __launch_bounds__(256) void k_proj_sq(const float* __restrict__ ap,   // (DK,F)
                                                 const float* __restrict__ emb,  // (B,F,N)
                                                 float* __restrict__ proj,       // (B,DK,N)
                                                 float* __restrict__ sqn) {      // (B,N)
  int t = threadIdx.x;
  int b = blockIdx.y;
  int n = blockIdx.x * 64 + (t & 63);
  int dg = __builtin_amdgcn_readfirstlane(t >> 6);  // wave-uniform d-group
  const float* e = emb + (size_t)b * F * N + n;
  float acc[4] = {0.f, 0.f, 0.f, 0.f};
#pragma unroll 4
  for (int f = 0; f < F; ++f) {
    float x = e[(size_t)f * N];
#pragma unroll
    for (int q = 0; q < 4; ++q) acc[q] = fmaf(ap[(dg * 4 + q) * F + f], x, acc[q]);
  }
  float s = 0.f;
#pragma unroll
  for (int q = 0; q < 4; ++q) {
    proj[((size_t)b * DK + dg * 4 + q) * N + n] = acc[q];
    s = fmaf(acc[q], acc[q], s);
  }
  __shared__ float sp[4][64];
  sp[dg][t & 63] = s;
  __syncthreads();
  if (t < 64) sqn[(size_t)b * N + blockIdx.x * 64 + t] =
      sp[0][t] + sp[1][t] + sp[2][t] + sp[3][t];
}

// ---------------- readout: pool + instance-norm + fcl + sigmoid ----------------
__global__ __launch_bounds__(256) void k_readout(const float* __restrict__ emb,
                                                 const float* __restrict__ fw,
                                                 const float* __restrict__ fb,
                                                 float* __restrict__ out) {
  int b = blockIdx.x, t = threadIdx.x;
  int f = t & 63, part = t >> 6;
  const float* p = emb + ((size_t)b * F + f) * N;
  float s = 0.f;
  for (int i = part * (N / 4); i < (part + 1) * (N / 4); ++i) s += p[i];
  __shared__ float red[4][64];
  red[part][f] = s;
  __syncthreads();
  if (t == 0) {
    float pooled[64];
    float mn = 0.f;
    for (int q = 0; q < 64; ++q) {
      float po = (red[0][q] + red[1][q] + red[2][q] + red[3][q]) / (float)N;
      pooled[q] = po;
      mn += po;
    }
    mn /= 64.f;
    float var = 0.f;
    for (int q = 0; q < 64; ++q) {
      float d2 = pooled[q] - mn;
      var = fmaf(d2, d2, var);
    }
    var /= 64.f;
    float r = rsqrtf(var + EPS);
    float lg = fb[0];
    for (int q = 0; q < 64; ++q) lg = fmaf((pooled[q] - mn) * r, fw[q], lg);
    out[b] = 1.f / (1.f + __expf(-lg));
  }
}

}  // namespace

extern "C" void kernel_launch(void* const* d_in, const int* in_sizes, int n_in,
                              void* d_out, int out_size, void* d_ws, size_t ws_size,
                              hipStream_t stream) {
  const float* emb_in   = (const float*)d_in[0];
  const float* sigma    = (const float*)d_in[1];
  const float* fst_w    = (const float*)d_in[2];
  const float* fst_b    = (const float*)d_in[3];
  const float* fst_wres = (const float*)d_in[4];
  const float* fst_bres = (const float*)d_in[5];
  const float* adj_proj = (const float*)d_in[6];
  const float* w        = (const float*)d_in[7];
  const float* bw       = (const float*)d_in[8];
  const float* wres     = (const float*)d_in[9];
  const float* bres     = (const float*)d_in[10];
  const float* fcl_w    = (const float*)d_in[11];
  const float* fcl_b    = (const float*)d_in[12];

  // runtime chunk count for big layers, gated on workspace size
  auto need_bytes = [](int nch) -> size_t {
    size_t f = 0;
    f += B * N;                                        // sqn
    f += (size_t)((nch > NCH0) ? nch : NCH0) * B * N;  // pdeg
    size_t pd1 = (size_t)nch * B * F * N, pd0 = (size_t)NCH0 * B * F0 * N;
    f += (pd1 > pd0) ? pd1 : pd0;                      // pdmsg
    f += 3 * (size_t)B * F * N;                        // embA, embB, Vb
    f += (size_t)B * DK * N;                           // projb
    return f * 4;
  };
  int nch = (ws_size >= need_bytes(8)) ? 8 : 4;
  int cpx = nch * B / 8;

  float* ws = (float*)d_ws;
  float* sqn   = ws;  ws += B * N;
  float* pdeg  = ws;  ws += (size_t)((nch > NCH0) ? nch : NCH0) * B * N;
  size_t pd1 = (size_t)nch * B * F * N, pd0 = (size_t)NCH0 * B * F0 * N;
  float* pdmsg = ws;  ws += (pd1 > pd0) ? pd1 : pd0;
  float* embA  = ws;  ws += (size_t)B * F * N;
  float* embB  = ws;  ws += (size_t)B * F * N;
  float* Vb    = ws;  ws += (size_t)B * F * N;
  float* projb = ws;  ws += (size_t)B * DK * N;

  constexpr int CB0 = (B * F0 * N / 4 + B * N / 4 + 255) / 256;  // layer-0 combine grid
  constexpr int CB1 = (B * F * N / 4 + B * N / 4 + 255) / 256;   // big-layer combine grid

  // ---- layer 0 (input adjacency with sigma) ----
  k_sqnorm<F0><<<dim3(B * N / 256), 256, 0, stream>>>(emb_in, sqn);
  k_adj0<<<dim3(N / 256, NCH0, B), 256, 0, stream>>>(emb_in, sqn, sigma, pdmsg, pdeg);
  k_combine<NCH0, F0><<<dim3(CB0), 256, 0, stream>>>(pdmsg, pdeg);
  k_gopconv<F0><<<dim3(N / 64, B), 256, 0, stream>>>(
      emb_in, pdmsg, pdeg, fst_w, fst_b, fst_wres, fst_bres, embA);

  // ---- layers 1..2 (learned adjacency) ----
  const float* src = embA;
  float* dst = embB;
  for (int i = 0; i < 2; ++i) {
    k_proj_sq<<<dim3(N / 64, B), 256, 0, stream>>>(adj_proj + (size_t)i * DK * F, src,
                                                   projb, sqn);
    k_norm<<<dim3(B * F), 256, 0, stream>>>(src, Vb);
    k_adjmsg<<<dim3(MT * nch * B), 256, 0, stream>>>(projb, sqn, Vb, pdmsg, pdeg, nch, cpx);
    if (nch == 8) {
      k_combine<8, F><<<dim3(CB1), 256, 0, stream>>>(pdmsg, pdeg);
    } else {
      k_combine<4, F><<<dim3(CB1), 256, 0, stream>>>(pdmsg, pdeg);
    }
    k_gopconv<F><<<dim3(N / 64, B), 256, 0, stream>>>(
        Vb, pdmsg, pdeg, w + (size_t)i * F * 2 * F, bw + (size_t)i * F,
        wres + (size_t)i * F * F, bres + (size_t)i * F, dst);
    float* tmp = (float*)src;
    src = dst;
    dst = tmp;
  }

  k_readout<<<dim3(B), 256, 0, stream>>>(src, fcl_w, fcl_b, (float*)d_out);
}

// Round 8
// 185.252 us; speedup vs baseline: 1.6638x; 1.2668x over previous
//
#include <hip/hip_runtime.h>
#include <hip/hip_bf16.h>
#include <math.h>

namespace {

constexpr int B  = 4;
constexpr int N  = 2048;
constexpr int F0 = 6;
constexpr int F  = 64;
constexpr int DK = 16;
constexpr float EPS = 1e-5f;
constexpr int NCH0 = 16;  // n-chunks, layer-0 adjacency
constexpr int MT   = N / 64;  // m-tiles for big layers

typedef float fx4 __attribute__((ext_vector_type(4)));  // native vec for nontemporal builtins
typedef __attribute__((ext_vector_type(8)))  short bf16x8;   // MFMA A/B frag (8 bf16 = 4 VGPR)
typedef __attribute__((ext_vector_type(4)))  short bf16x4;   // b64 LDS chunk
typedef __attribute__((ext_vector_type(16))) float f32x16;   // MFMA C/D

__device__ inline short f2bf(float x, float* xr) {
  __hip_bfloat16 h = __float2bfloat16(x);   // RNE
  *xr = __bfloat162float(h);
  short s; __builtin_memcpy(&s, &h, 2);
  return s;
}
__device__ inline short f2bf(float x) {
  __hip_bfloat16 h = __float2bfloat16(x);
  short s; __builtin_memcpy(&s, &h, 2);
  return s;
}

// ---------------- squared norms per node ----------------
template<int D>
__global__ __launch_bounds__(256) void k_sqnorm(const float* __restrict__ x,
                                                float* __restrict__ sqn) {
  int idx = blockIdx.x * 256 + threadIdx.x;
  if (idx >= B * N) return;
  int b = idx >> 11;
  int n = idx & (N - 1);
  const float* xp = x + (size_t)b * D * N + n;
  float s = 0.f;
#pragma unroll
  for (int d = 0; d < D; ++d) { float v = xp[(size_t)d * N]; s = fmaf(v, v, s); }
  sqn[idx] = s;
}

// ---------------- layer-0 fused adjacency + deg + adj_msg (D=F=6, fp32) ----------------
__global__ __launch_bounds__(256) void k_adj0(const float* __restrict__ x,
                                              const float* __restrict__ sqn,
                                              const float* __restrict__ sigma,
                                              float* __restrict__ pdmsg,  // (NCH0,B,F0,N)
                                              float* __restrict__ pdeg) { // (NCH0,B,N)
  constexpr int NC = N / NCH0;  // 128
  int t = threadIdx.x;
  int m = blockIdx.x * 256 + t;
  int ch = blockIdx.y, b = blockIdx.z;
  float sg = sigma[0];
  float inv_s2 = 1.f / (sg * sg);
  const float* xb = x + (size_t)b * F0 * N;
  float pm[F0];
#pragma unroll
  for (int d = 0; d < F0; ++d) pm[d] = xb[(size_t)d * N + m];
  float sqm = sqn[b * N + m];
  float acc[F0] = {};
  float deg = 0.f;
  __shared__ __align__(16) float xt[64][8];
  int n0 = ch * NC;
  for (int nt = 0; nt < NC; nt += 64) {
    __syncthreads();
    for (int e = t; e < F0 * 64; e += 256) {
      int d = e >> 6, nn = e & 63;
      xt[nn][d] = xb[(size_t)d * N + n0 + nt + nn];
    }
    if (t < 64) xt[t][6] = sqn[b * N + n0 + nt + t];
    __syncthreads();
#pragma unroll 2
    for (int nn = 0; nn < 64; ++nn) {
      float4 p0 = *(const float4*)&xt[nn][0];
      float4 p1 = *(const float4*)&xt[nn][4];
      float g = fmaf(pm[0], p0.x, 0.f);
      g = fmaf(pm[1], p0.y, g);
      g = fmaf(pm[2], p0.z, g);
      g = fmaf(pm[3], p0.w, g);
      g = fmaf(pm[4], p1.x, g);
      g = fmaf(pm[5], p1.y, g);
      float dist = fmaxf(sqm + p1.z - 2.f * g, 0.f);
      float a = __expf(-dist * inv_s2);
      deg += a;
      acc[0] = fmaf(a, p0.x, acc[0]);
      acc[1] = fmaf(a, p0.y, acc[1]);
      acc[2] = fmaf(a, p0.z, acc[2]);
      acc[3] = fmaf(a, p0.w, acc[3]);
      acc[4] = fmaf(a, p1.x, acc[4]);
      acc[5] = fmaf(a, p1.y, acc[5]);
    }
  }
  size_t base = (size_t)ch * B + b;
#pragma unroll
  for (int d = 0; d < F0; ++d) pdmsg[(base * F0 + d) * N + m] = acc[d];
  pdeg[base * N + m] = deg;
}

// ---------------- big-layer adjacency+deg+PV via bf16 MFMA (D=16, F=64) ----------------
// Gram: one mfma_f32_32x32x16_bf16 per wave per 64-tile quadrant (K=16=DK exact).
// sqm/sqn computed IN-KERNEL from the bf16-rounded proj so dist(m,m)==0 exactly.
// adj -> bf16 -> LDS transpose tile -> PV B-operand; V cvt'd to bf16 at staging.
// C/D layout (m74/m101-verified): col=lane&31, row=(reg&3)+8*(reg>>2)+4*(lane>>5).
__global__ __launch_bounds__(256, 4) void k_adjmsg(const float* __restrict__ proj,
                                                   const float* __restrict__ V,
                                                   float* __restrict__ pdmsg,  // (nch,B,F,N)
                                                   float* __restrict__ pdeg,   // (nch,B,N)
                                                   int nch, int cpx) {
  const int NCb = N / nch;
  int i = blockIdx.x;
  int xcd = i & 7;
  int j = i >> 3;
  int lc = j / MT;
  int mtile = j - lc * MT;
  int combo = xcd * cpx + lc;  // bijective XCD swizzle
  int ch = combo >> 2;
  int b  = combo & 3;
  int M0 = mtile * 64;
  int n0 = ch * NCb;

  int t = threadIdx.x;
  int w = t >> 6, l = t & 63;
  int l31 = l & 31, lh = l >> 5;
  int mq = w & 1, nq = w >> 1;    // gram quadrant (m,n)
  int fq = w & 1, mq2 = w >> 1;   // PV quadrant (f,m)

  const float* pb = proj + (size_t)b * DK * N;
  const float* vb = V + (size_t)b * F * N;

  __shared__ __align__(16) float pmS[DK][64];
  __shared__ __align__(16) float pnS[DK][64];
  __shared__ __align__(16) short adjT[64][68];  // bf16 adj [m][n], pad 68 (2-way banks)
  __shared__ __align__(16) short vS[64][68];    // bf16 V   [f][n]
  __shared__ float sqmS[64];
  __shared__ float degS[2][64];

  // ---- stage m-tile proj, build A-frag (once), sqm from ROUNDED values ----
  {
    int d = t >> 4, m4b = (t & 15) * 4;
    *(float4*)&pmS[d][m4b] = *(const float4*)&pb[(size_t)d * N + M0 + m4b];
  }
  __syncthreads();
  bf16x8 afrag;
  {
    int am = l31 + 32 * mq;
    float sq = 0.f;
#pragma unroll
    for (int i2 = 0; i2 < 8; ++i2) {
      float xr;
      afrag[i2] = f2bf(pmS[lh * 8 + i2][am], &xr);
      sq = fmaf(xr, xr, sq);
    }
    sq += __shfl_xor(sq, 32);
    if (l < 32) sqmS[am] = sq;
  }
  __syncthreads();
  float sqmr[16];
#pragma unroll
  for (int r = 0; r < 16; ++r)
    sqmr[r] = sqmS[(r & 3) + 8 * (r >> 2) + 4 * lh + 32 * mq];

  f32x16 acc;
#pragma unroll
  for (int r = 0; r < 16; ++r) acc[r] = 0.f;
  float pdm[16];
#pragma unroll
  for (int r = 0; r < 16; ++r) pdm[r] = 0.f;

  for (int nt = 0; nt < NCb; nt += 64) {
    __syncthreads();  // prev iteration's readers of pnS/vS/adjT done
    {  // stage proj n-tile fp32
      int d = t >> 4, n4b = (t & 15) * 4;
      *(float4*)&pnS[d][n4b] = *(const float4*)&pb[(size_t)d * N + n0 + nt + n4b];
    }
    {  // stage V as bf16 (cvt in flight)
      int f = t >> 2, nb16 = (t & 3) * 16;
#pragma unroll
      for (int jj = 0; jj < 4; ++jj) {
        float4 v4 = *(const float4*)&vb[(size_t)f * N + n0 + nt + nb16 + 4 * jj];
        bf16x4 o;
        o[0] = f2bf(v4.x); o[1] = f2bf(v4.y); o[2] = f2bf(v4.z); o[3] = f2bf(v4.w);
        *(bf16x4*)&vS[f][nb16 + 4 * jj] = o;
      }
    }
    __syncthreads();
    // ---- gram via MFMA + exp -> adjT (bf16) ----
    bf16x8 bfrag;
    float sqn = 0.f;
    {
      int bn = l31 + 32 * nq;
#pragma unroll
      for (int i2 = 0; i2 < 8; ++i2) {
        float xr;
        bfrag[i2] = f2bf(pnS[lh * 8 + i2][bn], &xr);
        sqn = fmaf(xr, xr, sqn);
      }
      sqn += __shfl_xor(sqn, 32);
    }
    f32x16 gz;
#pragma unroll
    for (int r = 0; r < 16; ++r) gz[r] = 0.f;
    f32x16 g = __builtin_amdgcn_mfma_f32_32x32x16_bf16(afrag, bfrag, gz, 0, 0, 0);
    int ncol = l31 + 32 * nq;
#pragma unroll
    for (int r = 0; r < 16; ++r) {
      int m = (r & 3) + 8 * (r >> 2) + 4 * lh + 32 * mq;
      float dist = fmaxf(sqmr[r] + sqn - 2.f * g[r], 0.f);
      float a = __expf(-dist);
      pdm[r] += a;
      adjT[m][ncol] = f2bf(a);
    }
    __syncthreads();
    // ---- PV via MFMA: acc[f][m] += sum_n V[f][n] * adj[m][n] ----
#pragma unroll
    for (int kk = 0; kk < 4; ++kk) {
      int nb = kk * 16 + lh * 8;
      int fA = l31 + 32 * fq;
      int mB = l31 + 32 * mq2;
      bf16x4 alo = *(const bf16x4*)&vS[fA][nb];
      bf16x4 ahi = *(const bf16x4*)&vS[fA][nb + 4];
      bf16x4 blo = *(const bf16x4*)&adjT[mB][nb];
      bf16x4 bhi = *(const bf16x4*)&adjT[mB][nb + 4];
      bf16x8 af2, bf2;
#pragma unroll
      for (int i2 = 0; i2 < 4; ++i2) {
        af2[i2] = alo[i2]; af2[i2 + 4] = ahi[i2];
        bf2[i2] = blo[i2]; bf2[i2 + 4] = bhi[i2];
      }
      acc = __builtin_amdgcn_mfma_f32_32x32x16_bf16(af2, bf2, acc, 0, 0, 0);
    }
  }
  // ---- deg: reduce over n-lanes, cross-wave via LDS ----
#pragma unroll
  for (int r = 0; r < 16; ++r) {
    pdm[r] += __shfl_xor(pdm[r], 1);
    pdm[r] += __shfl_xor(pdm[r], 2);
    pdm[r] += __shfl_xor(pdm[r], 4);
    pdm[r] += __shfl_xor(pdm[r], 8);
    pdm[r] += __shfl_xor(pdm[r], 16);
  }
  if (l31 == 0) {
#pragma unroll
    for (int r = 0; r < 16; ++r)
      degS[nq][(r & 3) + 8 * (r >> 2) + 4 * lh + 32 * mq] = pdm[r];
  }
  __syncthreads();
  if (t < 64) {
    float s = degS[0][t] + degS[1][t];
    __builtin_nontemporal_store(s, &pdeg[(size_t)combo * N + M0 + t]);
  }
  // ---- PV output (NT stores; coalesced 128B per half-wave) ----
  float* pdm_g = pdmsg + (size_t)combo * F * N;
  int m_out = l31 + 32 * mq2;
#pragma unroll
  for (int r = 0; r < 16; ++r) {
    int f_r = (r & 3) + 8 * (r >> 2) + 4 * lh + 32 * fq;
    __builtin_nontemporal_store(acc[r], &pdm_g[(size_t)f_r * N + M0 + m_out]);
  }
}

// ---------------- in-place chunk reduce: chunk 0 += chunks 1..CH-1 ----------------
template<int CH, int FF>
__global__ __launch_bounds__(256) void k_combine(float* __restrict__ pdmsg,
                                                 float* __restrict__ pdeg) {
  constexpr int E1 = B * FF * N / 4;
  constexpr int E2 = B * N / 4;
  int idx = blockIdx.x * 256 + threadIdx.x;
  if (idx < E1) {
    fx4* p = (fx4*)pdmsg;
    fx4 s = __builtin_nontemporal_load(&p[idx]);
#pragma unroll
    for (int c = 1; c < CH; ++c) s += __builtin_nontemporal_load(&p[(size_t)c * E1 + idx]);
    p[idx] = s;
  } else if (idx < E1 + E2) {
    int j2 = idx - E1;
    fx4* p = (fx4*)pdeg;
    fx4 s = __builtin_nontemporal_load(&p[j2]);
#pragma unroll
    for (int c = 1; c < CH; ++c) s += __builtin_nontemporal_load(&p[(size_t)c * E2 + j2]);
    p[j2] = s;
  }
}

// ---------------- gopconv epilogue on COMBINED dmsg/deg ----------------
template<int FIN>
__global__ __launch_bounds__(256) void k_gopconv(const float* __restrict__ X,
                                                 const float* __restrict__ dmsg,  // (B,FIN,N)
                                                 const float* __restrict__ deg,   // (B,N)
                                                 const float* __restrict__ W,     // (64,2*FIN)
                                                 const float* __restrict__ bias,  // (64)
                                                 const float* __restrict__ Wres,  // (64,FIN)
                                                 const float* __restrict__ bres,  // (64)
                                                 float* __restrict__ out) {       // (B,64,N)
  int t = threadIdx.x;
  int m = blockIdx.x * 64 + (t & 63);
  int og = __builtin_amdgcn_readfirstlane(t >> 6);
  int b = blockIdx.y;
  float dg = deg[(size_t)b * N + m];
  float cacc[16], racc[16];
#pragma unroll
  for (int k = 0; k < 16; ++k) {
    cacc[k] = bias[og * 16 + k];
    racc[k] = bres[og * 16 + k];
  }
#pragma unroll 2
  for (int f = 0; f < FIN; ++f) {
    float x = X[((size_t)b * FIN + f) * N + m];
    float dm = dmsg[((size_t)b * FIN + f) * N + m];
    float c0 = x * dg;
#pragma unroll
    for (int k = 0; k < 16; ++k) {
      int o = og * 16 + k;
      cacc[k] = fmaf(W[(size_t)o * 2 * FIN + f], c0, cacc[k]);
      cacc[k] = fmaf(W[(size_t)o * 2 * FIN + FIN + f], dm, cacc[k]);
      racc[k] = fmaf(Wres[(size_t)o * FIN + f], x, racc[k]);
    }
  }
#pragma unroll
  for (int k = 0; k < 16; ++k) {
    out[((size_t)b * F + og * 16 + k) * N + m] = fmaxf(cacc[k], 0.f) + racc[k];
  }
}

// ---------------- fused spatialnorm ----------------
__global__ __launch_bounds__(256) void k_norm(const float* __restrict__ emb,
                                              float* __restrict__ Vout) {
  int row = blockIdx.x;
  int t = threadIdx.x;
  const float4* p = (const float4*)(emb + (size_t)row * N);
  float4* o = (float4*)(Vout + (size_t)row * N);
  __shared__ __align__(16) float4 buf[N / 4];
  float s = 0.f, s2 = 0.f;
#pragma unroll
  for (int i = t; i < N / 4; i += 256) {
    float4 v = p[i];
    buf[i] = v;
    s += v.x + v.y + v.z + v.w;
    s2 = fmaf(v.x, v.x, s2); s2 = fmaf(v.y, v.y, s2);
    s2 = fmaf(v.z, v.z, s2); s2 = fmaf(v.w, v.w, s2);
  }
#pragma unroll
  for (int off = 1; off < 64; off <<= 1) {
    s += __shfl_xor(s, off);
    s2 += __shfl_xor(s2, off);
  }
  __shared__ float rs[4], rq[4], stat[2];
  if ((t & 63) == 0) { rs[t >> 6] = s; rq[t >> 6] = s2; }
  __syncthreads();
  if (t == 0) {
    float S = rs[0] + rs[1] + rs[2] + rs[3];
    float Q = rq[0] + rq[1] + rq[2] + rq[3];
    float mn = S / N;
    float var = Q / N - mn * mn;
    stat[0] = mn;
    stat[1] = rsqrtf(var + EPS);
  }
  __syncthreads();
  float mn = stat[0], r = stat[1];
#pragma unroll
  for (int i = t; i < N / 4; i += 256) {
    float4 v = buf[i];
    o[i] = make_float4((v.x - mn) * r, (v.y - mn) * r, (v.z - mn) * r, (v.w - mn) * r);
  }
}

// ---------------- fused proj = adj_proj[i] @ emb (+ sqnorm, legacy) ----------------
__global__ __launch_bounds__(256) void k_proj_sq(const float* __restrict__ ap,
                                                 const float* __restrict__ emb,
                                                 float* __restrict__ proj,
                                                 float* __restrict__ sqn) {
  int t = threadIdx.x;
  int b = blockIdx.y;
  int n = blockIdx.x * 64 + (t & 63);
  int dg = __builtin_amdgcn_readfirstlane(t >> 6);
  const float* e = emb + (size_t)b * F * N + n;
  float acc[4] = {0.f, 0.f, 0.f, 0.f};
#pragma unroll 4
  for (int f = 0; f < F; ++f) {
    float x = e[(size_t)f * N];
#pragma unroll
    for (int q = 0; q < 4; ++q) acc[q] = fmaf(ap[(dg * 4 + q) * F + f], x, acc[q]);
  }
  float s = 0.f;
#pragma unroll
  for (int q = 0; q < 4; ++q) {
    proj[((size_t)b * DK + dg * 4 + q) * N + n] = acc[q];
    s = fmaf(acc[q], acc[q], s);
  }
  __shared__ float sp[4][64];
  sp[dg][t & 63] = s;
  __syncthreads();
  if (t < 64) sqn[(size_t)b * N + blockIdx.x * 64 + t] =
      sp[0][t] + sp[1][t] + sp[2][t] + sp[3][t];
}

// ---------------- readout ----------------
__global__ __launch_bounds__(256) void k_readout(const float* __restrict__ emb,
                                                 const float* __restrict__ fw,
                                                 const float* __restrict__ fb,
                                                 float* __restrict__ out) {
  int b = blockIdx.x, t = threadIdx.x;
  int f = t & 63, part = t >> 6;
  const float* p = emb + ((size_t)b * F + f) * N;
  float s = 0.f;
  for (int i = part * (N / 4); i < (part + 1) * (N / 4); ++i) s += p[i];
  __shared__ float red[4][64];
  red[part][f] = s;
  __syncthreads();
  if (t == 0) {
    float pooled[64];
    float mn = 0.f;
    for (int q = 0; q < 64; ++q) {
      float po = (red[0][q] + red[1][q] + red[2][q] + red[3][q]) / (float)N;
      pooled[q] = po;
      mn += po;
    }
    mn /= 64.f;
    float var = 0.f;
    for (int q = 0; q < 64; ++q) {
      float d2 = pooled[q] - mn;
      var = fmaf(d2, d2, var);
    }
    var /= 64.f;
    float r = rsqrtf(var + EPS);
    float lg = fb[0];
    for (int q = 0; q < 64; ++q) lg = fmaf((pooled[q] - mn) * r, fw[q], lg);
    out[b] = 1.f / (1.f + __expf(-lg));
  }
}

}  // namespace

extern "C" void kernel_launch(void* const* d_in, const int* in_sizes, int n_in,
                              void* d_out, int out_size, void* d_ws, size_t ws_size,
                              hipStream_t stream) {
  const float* emb_in   = (const float*)d_in[0];
  const float* sigma    = (const float*)d_in[1];
  const float* fst_w    = (const float*)d_in[2];
  const float* fst_b    = (const float*)d_in[3];
  const float* fst_wres = (const float*)d_in[4];
  const float* fst_bres = (const float*)d_in[5];
  const float* adj_proj = (const float*)d_in[6];
  const float* w        = (const float*)d_in[7];
  const float* bw       = (const float*)d_in[8];
  const float* wres     = (const float*)d_in[9];
  const float* bres     = (const float*)d_in[10];
  const float* fcl_w    = (const float*)d_in[11];
  const float* fcl_b    = (const float*)d_in[12];

  auto need_bytes = [](int nch) -> size_t {
    size_t f = 0;
    f += B * N;
    f += (size_t)((nch > NCH0) ? nch : NCH0) * B * N;
    size_t pd1 = (size_t)nch * B * F * N, pd0 = (size_t)NCH0 * B * F0 * N;
    f += (pd1 > pd0) ? pd1 : pd0;
    f += 3 * (size_t)B * F * N;
    f += (size_t)B * DK * N;
    return f * 4;
  };
  int nch = (ws_size >= need_bytes(8)) ? 8 : 4;
  int cpx = nch * B / 8;

  float* ws = (float*)d_ws;
  float* sqn   = ws;  ws += B * N;
  float* pdeg  = ws;  ws += (size_t)((nch > NCH0) ? nch : NCH0) * B * N;
  size_t pd1 = (size_t)nch * B * F * N, pd0 = (size_t)NCH0 * B * F0 * N;
  float* pdmsg = ws;  ws += (pd1 > pd0) ? pd1 : pd0;
  float* embA  = ws;  ws += (size_t)B * F * N;
  float* embB  = ws;  ws += (size_t)B * F * N;
  float* Vb    = ws;  ws += (size_t)B * F * N;
  float* projb = ws;  ws += (size_t)B * DK * N;

  constexpr int CB0 = (B * F0 * N / 4 + B * N / 4 + 255) / 256;
  constexpr int CB1 = (B * F * N / 4 + B * N / 4 + 255) / 256;

  // ---- layer 0 (input adjacency with sigma, fp32) ----
  k_sqnorm<F0><<<dim3(B * N / 256), 256, 0, stream>>>(emb_in, sqn);
  k_adj0<<<dim3(N / 256, NCH0, B), 256, 0, stream>>>(emb_in, sqn, sigma, pdmsg, pdeg);
  k_combine<NCH0, F0><<<dim3(CB0), 256, 0, stream>>>(pdmsg, pdeg);
  k_gopconv<F0><<<dim3(N / 64, B), 256, 0, stream>>>(
      emb_in, pdmsg, pdeg, fst_w, fst_b, fst_wres, fst_bres, embA);

  // ---- layers 1..2 (learned adjacency, MFMA) ----
  const float* src = embA;
  float* dst = embB;
  for (int i = 0; i < 2; ++i) {
    k_proj_sq<<<dim3(N / 64, B), 256, 0, stream>>>(adj_proj + (size_t)i * DK * F, src,
                                                   projb, sqn);
    k_norm<<<dim3(B * F), 256, 0, stream>>>(src, Vb);
    k_adjmsg<<<dim3(MT * nch * B), 256, 0, stream>>>(projb, Vb, pdmsg, pdeg, nch, cpx);
    if (nch == 8) {
      k_combine<8, F><<<dim3(CB1), 256, 0, stream>>>(pdmsg, pdeg);
    } else {
      k_combine<4, F><<<dim3(CB1), 256, 0, stream>>>(pdmsg, pdeg);
    }
    k_gopconv<F><<<dim3(N / 64, B), 256, 0, stream>>>(
        Vb, pdmsg, pdeg, w + (size_t)i * F * 2 * F, bw + (size_t)i * F,
        wres + (size_t)i * F * F, bres + (size_t)i * F, dst);
    float* tmp = (float*)src;
    src = dst;
    dst = tmp;
  }

  k_readout<<<dim3(B), 256, 0, stream>>>(src, fcl_w, fcl_b, (float*)d_out);
}

// Round 9
// 138.015 us; speedup vs baseline: 2.2333x; 1.3423x over previous
//
#include <hip/hip_runtime.h>
#include <hip/hip_bf16.h>
#include <math.h>

namespace {

constexpr int B  = 4;
constexpr int N  = 2048;
constexpr int F0 = 6;
constexpr int F  = 64;
constexpr int DK = 16;
constexpr float EPS = 1e-5f;
constexpr int MT   = N / 64;  // m-tiles

typedef float fx4 __attribute__((ext_vector_type(4)));
typedef __attribute__((ext_vector_type(8)))  short bf16x8;
typedef __attribute__((ext_vector_type(4)))  short bf16x4;
typedef __attribute__((ext_vector_type(16))) float f32x16;

__device__ inline short f2bf(float x, float* xr) {
  __hip_bfloat16 h = __float2bfloat16(x);
  *xr = __bfloat162float(h);
  short s; __builtin_memcpy(&s, &h, 2);
  return s;
}
__device__ inline short f2bf(float x) {
  __hip_bfloat16 h = __float2bfloat16(x);
  short s; __builtin_memcpy(&s, &h, 2);
  return s;
}

// ---------------- layer-0 prep: proj0 = emb_in / sigma, zero-padded to DK rows ----------------
__global__ __launch_bounds__(256) void k_prep0(const float* __restrict__ emb_in,
                                               const float* __restrict__ sigma,
                                               float* __restrict__ proj0) {  // (B,DK,N)
  int idx = blockIdx.x * 256 + threadIdx.x;  // float4 units
  if (idx >= B * DK * N / 4) return;
  int row = idx >> 9;        // N/4 = 512
  int d = row & 15, b = row >> 4;
  fx4 v = {0.f, 0.f, 0.f, 0.f};
  if (d < F0) {
    float inv = 1.f / sigma[0];
    fx4 x = ((const fx4*)emb_in)[((size_t)b * F0 + d) * 512 + (idx & 511)];
    v = x * inv;
  }
  ((fx4*)proj0)[idx] = v;
}

// ---------------- weight-folding GEMMs: T[z] = {W1,W2,Wres}·X ; z==3: proj = Ap·Xp ----------------
// LDS-tiled: X-tile transposed [n][f] (+1 pad, conflict-free), W-set [o][f]; W reads broadcast.
template<int FIN>
__global__ __launch_bounds__(256) void k_wx(const float* __restrict__ Xw,  // (B,FIN,N) z<3
                                            const float* __restrict__ Xp,  // (B,FIN,N) z==3
                                            const float* __restrict__ Wc,  // (64,2*FIN)
                                            const float* __restrict__ Wr,  // (64,FIN)
                                            const float* __restrict__ Ap,  // (DK,FIN) or null
                                            float* __restrict__ T,         // (B,3,64,N)
                                            float* __restrict__ projb) {   // (B,DK,N)
  int z = blockIdx.z, b = blockIdx.y, n0 = blockIdx.x * 64;
  int t = threadIdx.x, n = t & 63, og = t >> 6;
  __shared__ float xS[64][FIN + 1];
  __shared__ float wS[64][FIN + 1];
  const float* X = (z == 3) ? Xp : Xw;
  for (int e = t; e < FIN * 64; e += 256) {
    int f = e >> 6, nn = e & 63;
    xS[nn][f] = X[((size_t)b * FIN + f) * N + n0 + nn];
  }
  {
    const float* base; int ld, off, OUT;
    if (z == 0)      { base = Wc; ld = 2 * FIN; off = 0;   OUT = 64; }
    else if (z == 1) { base = Wc; ld = 2 * FIN; off = FIN; OUT = 64; }
    else if (z == 2) { base = Wr; ld = FIN;     off = 0;   OUT = 64; }
    else             { base = Ap; ld = FIN;     off = 0;   OUT = DK; }
    for (int e = t; e < OUT * FIN; e += 256) {
      int o = e / FIN, f = e - o * FIN;
      wS[o][f] = base[(size_t)o * ld + off + f];
    }
  }
  __syncthreads();
  if (z < 3) {
    float cacc[16] = {};
#pragma unroll 4
    for (int f = 0; f < FIN; ++f) {
      float x = xS[n][f];
#pragma unroll
      for (int k = 0; k < 16; ++k)
        cacc[k] = fmaf(wS[og * 16 + k][f], x, cacc[k]);
    }
#pragma unroll
    for (int k = 0; k < 16; ++k)
      T[(((size_t)b * 3 + z) * 64 + og * 16 + k) * N + n0 + n] = cacc[k];
  } else {
    float cacc[4] = {};
#pragma unroll 4
    for (int f = 0; f < FIN; ++f) {
      float x = xS[n][f];
#pragma unroll
      for (int k = 0; k < 4; ++k)
        cacc[k] = fmaf(wS[og * 4 + k][f], x, cacc[k]);
    }
#pragma unroll
    for (int k = 0; k < 4; ++k)
      projb[((size_t)b * DK + og * 4 + k) * N + n0 + n] = cacc[k];
  }
}

// ---------------- adjacency+deg+PV via bf16 MFMA (PV operand = W2·V from T) ----------------
__global__ __launch_bounds__(256, 4) void k_adjmsg(const float* __restrict__ proj,
                                                   const float* __restrict__ T,
                                                   float* __restrict__ pdmsg,  // (nch,B,F,N)
                                                   float* __restrict__ pdeg,   // (nch,B,N)
                                                   int nch, int cpx) {
  const int NCb = N / nch;
  int i = blockIdx.x;
  int xcd = i & 7;
  int j = i >> 3;
  int lc = j / MT;
  int mtile = j - lc * MT;
  int combo = xcd * cpx + lc;  // bijective XCD swizzle
  int ch = combo >> 2;
  int b  = combo & 3;
  int M0 = mtile * 64;
  int n0 = ch * NCb;

  int t = threadIdx.x;
  int w = t >> 6, l = t & 63;
  int l31 = l & 31, lh = l >> 5;
  int mq = w & 1, nq = w >> 1;
  int fq = w & 1, mq2 = w >> 1;

  const float* pb = proj + (size_t)b * DK * N;
  const float* vb = T + ((size_t)b * 3 + 1) * (size_t)F * N;  // W2·V slice

  __shared__ __align__(16) float pmS[DK][64];
  __shared__ __align__(16) float pnS[DK][64];
  __shared__ __align__(16) short adjT[64][68];
  __shared__ __align__(16) short vS[64][68];
  __shared__ float sqmS[64];
  __shared__ float degS[2][64];

  {
    int d = t >> 4, m4b = (t & 15) * 4;
    *(float4*)&pmS[d][m4b] = *(const float4*)&pb[(size_t)d * N + M0 + m4b];
  }
  __syncthreads();
  bf16x8 afrag;
  {
    int am = l31 + 32 * mq;
    float sq = 0.f;
#pragma unroll
    for (int i2 = 0; i2 < 8; ++i2) {
      float xr;
      afrag[i2] = f2bf(pmS[lh * 8 + i2][am], &xr);
      sq = fmaf(xr, xr, sq);
    }
    sq += __shfl_xor(sq, 32);
    if (l < 32) sqmS[am] = sq;
  }
  __syncthreads();
  float sqmr[16];
#pragma unroll
  for (int r = 0; r < 16; ++r)
    sqmr[r] = sqmS[(r & 3) + 8 * (r >> 2) + 4 * lh + 32 * mq];

  f32x16 acc;
#pragma unroll
  for (int r = 0; r < 16; ++r) acc[r] = 0.f;
  float pdm[16];
#pragma unroll
  for (int r = 0; r < 16; ++r) pdm[r] = 0.f;

  for (int nt = 0; nt < NCb; nt += 64) {
    __syncthreads();
    {
      int d = t >> 4, n4b = (t & 15) * 4;
      *(float4*)&pnS[d][n4b] = *(const float4*)&pb[(size_t)d * N + n0 + nt + n4b];
    }
    {
      int f = t >> 2, nb16 = (t & 3) * 16;
#pragma unroll
      for (int jj = 0; jj < 4; ++jj) {
        float4 v4 = *(const float4*)&vb[(size_t)f * N + n0 + nt + nb16 + 4 * jj];
        bf16x4 o;
        o[0] = f2bf(v4.x); o[1] = f2bf(v4.y); o[2] = f2bf(v4.z); o[3] = f2bf(v4.w);
        *(bf16x4*)&vS[f][nb16 + 4 * jj] = o;
      }
    }
    __syncthreads();
    bf16x8 bfrag;
    float sqn = 0.f;
    {
      int bn = l31 + 32 * nq;
#pragma unroll
      for (int i2 = 0; i2 < 8; ++i2) {
        float xr;
        bfrag[i2] = f2bf(pnS[lh * 8 + i2][bn], &xr);
        sqn = fmaf(xr, xr, sqn);
      }
      sqn += __shfl_xor(sqn, 32);
    }
    f32x16 gz;
#pragma unroll
    for (int r = 0; r < 16; ++r) gz[r] = 0.f;
    f32x16 g = __builtin_amdgcn_mfma_f32_32x32x16_bf16(afrag, bfrag, gz, 0, 0, 0);
    int ncol = l31 + 32 * nq;
#pragma unroll
    for (int r = 0; r < 16; ++r) {
      int m = (r & 3) + 8 * (r >> 2) + 4 * lh + 32 * mq;
      float dist = fmaxf(sqmr[r] + sqn - 2.f * g[r], 0.f);
      float a = __expf(-dist);
      pdm[r] += a;
      adjT[m][ncol] = f2bf(a);
    }
    __syncthreads();
#pragma unroll
    for (int kk = 0; kk < 4; ++kk) {
      int nb = kk * 16 + lh * 8;
      int fA = l31 + 32 * fq;
      int mB = l31 + 32 * mq2;
      bf16x4 alo = *(const bf16x4*)&vS[fA][nb];
      bf16x4 ahi = *(const bf16x4*)&vS[fA][nb + 4];
      bf16x4 blo = *(const bf16x4*)&adjT[mB][nb];
      bf16x4 bhi = *(const bf16x4*)&adjT[mB][nb + 4];
      bf16x8 af2, bf2;
#pragma unroll
      for (int i2 = 0; i2 < 4; ++i2) {
        af2[i2] = alo[i2]; af2[i2 + 4] = ahi[i2];
        bf2[i2] = blo[i2]; bf2[i2 + 4] = bhi[i2];
      }
      acc = __builtin_amdgcn_mfma_f32_32x32x16_bf16(af2, bf2, acc, 0, 0, 0);
    }
  }
#pragma unroll
  for (int r = 0; r < 16; ++r) {
    pdm[r] += __shfl_xor(pdm[r], 1);
    pdm[r] += __shfl_xor(pdm[r], 2);
    pdm[r] += __shfl_xor(pdm[r], 4);
    pdm[r] += __shfl_xor(pdm[r], 8);
    pdm[r] += __shfl_xor(pdm[r], 16);
  }
  if (l31 == 0) {
#pragma unroll
    for (int r = 0; r < 16; ++r)
      degS[nq][(r & 3) + 8 * (r >> 2) + 4 * lh + 32 * mq] = pdm[r];
  }
  __syncthreads();
  if (t < 64) {
    float s = degS[0][t] + degS[1][t];
    __builtin_nontemporal_store(s, &pdeg[(size_t)combo * N + M0 + t]);
  }
  float* pdm_g = pdmsg + (size_t)combo * F * N;
  int m_out = l31 + 32 * mq2;
#pragma unroll
  for (int r = 0; r < 16; ++r) {
    int f_r = (r & 3) + 8 * (r >> 2) + 4 * lh + 32 * fq;
    __builtin_nontemporal_store(acc[r], &pdm_g[(size_t)f_r * N + M0 + m_out]);
  }
}

// ---------------- fused chunk-combine + epilogue (elementwise, massively parallel) ----------------
// out[o][m] = relu( sum_c pdmsg + (W1·V)[o][m]*deg[m] + bias[o] ) + (Wres·V)[o][m] + bres[o]
template<int CH>
__global__ __launch_bounds__(256) void k_ep(const float* __restrict__ pdmsg,
                                            const float* __restrict__ pdeg,
                                            const float* __restrict__ T,
                                            const float* __restrict__ bias,
                                            const float* __restrict__ bres,
                                            float* __restrict__ out) {
  int idx = blockIdx.x * 256 + threadIdx.x;  // float4 units, total B*F*N/4
  int row = idx >> 9;                        // N/4 = 512
  int c4 = idx & 511;
  int o = row & 63, b = row >> 6;
  fx4 dm = {0.f, 0.f, 0.f, 0.f};
  fx4 dg = {0.f, 0.f, 0.f, 0.f};
#pragma unroll
  for (int c = 0; c < CH; ++c) {
    dm += __builtin_nontemporal_load(&((const fx4*)pdmsg)[(((size_t)c * B + b) * 64 + o) * 512 + c4]);
    dg += ((const fx4*)pdeg)[((size_t)c * B + b) * 512 + c4];
  }
  fx4 t0 = ((const fx4*)T)[(((size_t)b * 3 + 0) * 64 + o) * 512 + c4];
  fx4 t2 = ((const fx4*)T)[(((size_t)b * 3 + 2) * 64 + o) * 512 + c4];
  float bi = bias[o], br = bres[o];
  fx4 r = dm + t0 * dg;
  fx4 ov;
#pragma unroll
  for (int j = 0; j < 4; ++j) ov[j] = fmaxf(r[j] + bi, 0.f) + t2[j] + br;
  ((fx4*)out)[((size_t)b * 64 + o) * 512 + c4] = ov;
}

// ---------------- fused spatialnorm ----------------
__global__ __launch_bounds__(256) void k_norm(const float* __restrict__ emb,
                                              float* __restrict__ Vout) {
  int row = blockIdx.x;
  int t = threadIdx.x;
  const float4* p = (const float4*)(emb + (size_t)row * N);
  float4* o = (float4*)(Vout + (size_t)row * N);
  __shared__ __align__(16) float4 buf[N / 4];
  float s = 0.f, s2 = 0.f;
#pragma unroll
  for (int i = t; i < N / 4; i += 256) {
    float4 v = p[i];
    buf[i] = v;
    s += v.x + v.y + v.z + v.w;
    s2 = fmaf(v.x, v.x, s2); s2 = fmaf(v.y, v.y, s2);
    s2 = fmaf(v.z, v.z, s2); s2 = fmaf(v.w, v.w, s2);
  }
#pragma unroll
  for (int off = 1; off < 64; off <<= 1) {
    s += __shfl_xor(s, off);
    s2 += __shfl_xor(s2, off);
  }
  __shared__ float rs[4], rq[4], stat[2];
  if ((t & 63) == 0) { rs[t >> 6] = s; rq[t >> 6] = s2; }
  __syncthreads();
  if (t == 0) {
    float S = rs[0] + rs[1] + rs[2] + rs[3];
    float Q = rq[0] + rq[1] + rq[2] + rq[3];
    float mn = S / N;
    float var = Q / N - mn * mn;
    stat[0] = mn;
    stat[1] = rsqrtf(var + EPS);
  }
  __syncthreads();
  float mn = stat[0], r = stat[1];
#pragma unroll
  for (int i = t; i < N / 4; i += 256) {
    float4 v = buf[i];
    o[i] = make_float4((v.x - mn) * r, (v.y - mn) * r, (v.z - mn) * r, (v.w - mn) * r);
  }
}

// ---------------- readout: pool + instance-norm + fcl + sigmoid (coalesced) ----------------
__global__ __launch_bounds__(256) void k_readout(const float* __restrict__ emb,
                                                 const float* __restrict__ fw,
                                                 const float* __restrict__ fb,
                                                 float* __restrict__ out) {
  int b = blockIdx.x, t = threadIdx.x, w = t >> 6, l = t & 63;
  __shared__ float red[64];
  for (int fr = w * 16; fr < w * 16 + 16; ++fr) {
    const fx4* p = (const fx4*)(emb + ((size_t)b * F + fr) * N);
    float s = 0.f;
#pragma unroll
    for (int i = l; i < N / 4; i += 64) {
      fx4 v = p[i];
      s += v.x + v.y + v.z + v.w;
    }
#pragma unroll
    for (int off = 1; off < 64; off <<= 1) s += __shfl_xor(s, off);
    if (l == 0) red[fr] = s;
  }
  __syncthreads();
  if (t == 0) {
    float pooled[64];
    float mn = 0.f;
    for (int q = 0; q < 64; ++q) {
      float po = red[q] / (float)N;
      pooled[q] = po;
      mn += po;
    }
    mn /= 64.f;
    float var = 0.f;
    for (int q = 0; q < 64; ++q) {
      float d2 = pooled[q] - mn;
      var = fmaf(d2, d2, var);
    }
    var /= 64.f;
    float r = rsqrtf(var + EPS);
    float lg = fb[0];
    for (int q = 0; q < 64; ++q) lg = fmaf((pooled[q] - mn) * r, fw[q], lg);
    out[b] = 1.f / (1.f + __expf(-lg));
  }
}

}  // namespace

extern "C" void kernel_launch(void* const* d_in, const int* in_sizes, int n_in,
                              void* d_out, int out_size, void* d_ws, size_t ws_size,
                              hipStream_t stream) {
  const float* emb_in   = (const float*)d_in[0];
  const float* sigma    = (const float*)d_in[1];
  const float* fst_w    = (const float*)d_in[2];
  const float* fst_b    = (const float*)d_in[3];
  const float* fst_wres = (const float*)d_in[4];
  const float* fst_bres = (const float*)d_in[5];
  const float* adj_proj = (const float*)d_in[6];
  const float* w        = (const float*)d_in[7];
  const float* bw       = (const float*)d_in[8];
  const float* wres     = (const float*)d_in[9];
  const float* bres     = (const float*)d_in[10];
  const float* fcl_w    = (const float*)d_in[11];
  const float* fcl_b    = (const float*)d_in[12];

  auto need_bytes = [](int nch) -> size_t {
    size_t f = 0;
    f += (size_t)nch * B * N;           // pdeg
    f += (size_t)nch * B * F * N;       // pdmsg
    f += 3 * (size_t)B * F * N;         // embA, embB, Vb
    f += (size_t)B * DK * N;            // projb
    f += 3 * (size_t)B * F * N;         // T
    return f * 4;
  };
  int nch = (ws_size >= need_bytes(8)) ? 8 : 4;
  int cpx = nch * B / 8;

  float* ws = (float*)d_ws;
  float* pdeg  = ws;  ws += (size_t)nch * B * N;
  float* pdmsg = ws;  ws += (size_t)nch * B * F * N;
  float* embA  = ws;  ws += (size_t)B * F * N;
  float* embB  = ws;  ws += (size_t)B * F * N;
  float* Vb    = ws;  ws += (size_t)B * F * N;
  float* projb = ws;  ws += (size_t)B * DK * N;
  float* T     = ws;  ws += 3 * (size_t)B * F * N;

  constexpr int EPB = (B * F * N / 4) / 256;  // 512 blocks for k_ep

  // ---- layer 0 (sigma folded into scaled+padded proj) ----
  k_prep0<<<dim3((B * DK * N / 4 + 255) / 256), 256, 0, stream>>>(emb_in, sigma, projb);
  k_wx<F0><<<dim3(N / 64, B, 3), 256, 0, stream>>>(emb_in, nullptr, fst_w, fst_wres,
                                                   nullptr, T, projb);
  k_adjmsg<<<dim3(MT * nch * B), 256, 0, stream>>>(projb, T, pdmsg, pdeg, nch, cpx);
  if (nch == 8)
    k_ep<8><<<dim3(EPB), 256, 0, stream>>>(pdmsg, pdeg, T, fst_b, fst_bres, embA);
  else
    k_ep<4><<<dim3(EPB), 256, 0, stream>>>(pdmsg, pdeg, T, fst_b, fst_bres, embA);

  // ---- layers 1..2 ----
  const float* src = embA;
  float* dst = embB;
  for (int i = 0; i < 2; ++i) {
    k_norm<<<dim3(B * F), 256, 0, stream>>>(src, Vb);
    k_wx<F><<<dim3(N / 64, B, 4), 256, 0, stream>>>(Vb, src, w + (size_t)i * F * 2 * F,
                                                    wres + (size_t)i * F * F,
                                                    adj_proj + (size_t)i * DK * F, T, projb);
    k_adjmsg<<<dim3(MT * nch * B), 256, 0, stream>>>(projb, T, pdmsg, pdeg, nch, cpx);
    if (nch == 8)
      k_ep<8><<<dim3(EPB), 256, 0, stream>>>(pdmsg, pdeg, T, bw + (size_t)i * F,
                                             bres + (size_t)i * F, dst);
    else
      k_ep<4><<<dim3(EPB), 256, 0, stream>>>(pdmsg, pdeg, T, bw + (size_t)i * F,
                                             bres + (size_t)i * F, dst);
    float* tmp = (float*)src;
    src = dst;
    dst = tmp;
  }

  k_readout<<<dim3(B), 256, 0, stream>>>(src, fcl_w, fcl_b, (float*)d_out);
}

// Round 10
// 131.074 us; speedup vs baseline: 2.3515x; 1.0530x over previous
//
#include <hip/hip_runtime.h>
#include <hip/hip_bf16.h>
#include <math.h>

namespace {

constexpr int B  = 4;
constexpr int N  = 2048;
constexpr int F0 = 6;
constexpr int F  = 64;
constexpr int DK = 16;
constexpr float EPS = 1e-5f;
constexpr int MT   = N / 64;  // m-tiles

typedef float fx4 __attribute__((ext_vector_type(4)));
typedef __attribute__((ext_vector_type(8)))  short bf16x8;
typedef __attribute__((ext_vector_type(4)))  short bf16x4;
typedef __attribute__((ext_vector_type(16))) float f32x16;

__device__ inline short f2bf(float x, float* xr) {
  __hip_bfloat16 h = __float2bfloat16(x);
  *xr = __bfloat162float(h);
  short s; __builtin_memcpy(&s, &h, 2);
  return s;
}
__device__ inline short f2bf(float x) {
  __hip_bfloat16 h = __float2bfloat16(x);
  short s; __builtin_memcpy(&s, &h, 2);
  return s;
}

// ---------------- layer-0 prep: proj0 = emb_in / sigma, zero-padded to DK rows ----------------
__global__ __launch_bounds__(256) void k_prep0(const float* __restrict__ emb_in,
                                               const float* __restrict__ sigma,
                                               float* __restrict__ proj0) {  // (B,DK,N)
  int idx = blockIdx.x * 256 + threadIdx.x;  // float4 units
  if (idx >= B * DK * N / 4) return;
  int row = idx >> 9;        // N/4 = 512
  int d = row & 15, b = row >> 4;
  fx4 v = {0.f, 0.f, 0.f, 0.f};
  if (d < F0) {
    float inv = 1.f / sigma[0];
    fx4 x = ((const fx4*)emb_in)[((size_t)b * F0 + d) * 512 + (idx & 511)];
    v = x * inv;
  }
  ((fx4*)proj0)[idx] = v;
}

// ---------------- spatialnorm stats (mean/rstd per (b,f) row) ----------------
__global__ __launch_bounds__(256) void k_stats(const float* __restrict__ emb,
                                               float* __restrict__ mean,
                                               float* __restrict__ rstd) {
  int row = blockIdx.x;  // b*F + f
  int t = threadIdx.x;
  const fx4* p = (const fx4*)(emb + (size_t)row * N);
  float s = 0.f, s2 = 0.f;
#pragma unroll
  for (int i = t; i < N / 4; i += 256) {
    fx4 v = p[i];
    s += v.x + v.y + v.z + v.w;
    s2 = fmaf(v.x, v.x, s2); s2 = fmaf(v.y, v.y, s2);
    s2 = fmaf(v.z, v.z, s2); s2 = fmaf(v.w, v.w, s2);
  }
#pragma unroll
  for (int off = 1; off < 64; off <<= 1) {
    s += __shfl_xor(s, off);
    s2 += __shfl_xor(s2, off);
  }
  __shared__ float rs[4], rq[4];
  if ((t & 63) == 0) { rs[t >> 6] = s; rq[t >> 6] = s2; }
  __syncthreads();
  if (t == 0) {
    float S = rs[0] + rs[1] + rs[2] + rs[3];
    float Q = rq[0] + rq[1] + rq[2] + rq[3];
    float mn = S / N;
    float var = Q / N - mn * mn;
    mean[row] = mn;
    rstd[row] = rsqrtf(var + EPS);
  }
}

// ---------------- weight-folding GEMMs with fused spatialnorm on load ----------------
// z<3: T[z] = {W1,W2,Wres}·norm(X); z==3: proj = Ap·X (raw X).
// wT transposed [f][o] -> per-f b128 broadcast reads (4 issues/f instead of 16 scalar).
template<int FIN, bool NORM>
__global__ __launch_bounds__(256) void k_wx(const float* __restrict__ X,   // (B,FIN,N)
                                            const float* __restrict__ mean,
                                            const float* __restrict__ rstd,
                                            const float* __restrict__ Wc,  // (64,2*FIN)
                                            const float* __restrict__ Wr,  // (64,FIN)
                                            const float* __restrict__ Ap,  // (DK,FIN) or null
                                            float* __restrict__ T,         // (B,3,64,N)
                                            float* __restrict__ projb) {   // (B,DK,N)
  int z = blockIdx.z, b = blockIdx.y, n0 = blockIdx.x * 64;
  int t = threadIdx.x, n = t & 63, og = t >> 6;
  __shared__ float xS[64][FIN + 1];
  __shared__ __align__(16) float wT[FIN][68];
  for (int e = t; e < FIN * 64; e += 256) {
    int f = e >> 6, nn = e & 63;
    float v = X[((size_t)b * FIN + f) * N + n0 + nn];
    if (NORM && z < 3) v = (v - mean[b * FIN + f]) * rstd[b * FIN + f];
    xS[nn][f] = v;
  }
  {
    const float* base; int ld, off, OUT;
    if (z == 0)      { base = Wc; ld = 2 * FIN; off = 0;   OUT = 64; }
    else if (z == 1) { base = Wc; ld = 2 * FIN; off = FIN; OUT = 64; }
    else if (z == 2) { base = Wr; ld = FIN;     off = 0;   OUT = 64; }
    else             { base = Ap; ld = FIN;     off = 0;   OUT = DK; }
    for (int e = t; e < OUT * FIN; e += 256) {
      int o = e / FIN, f = e - o * FIN;
      wT[f][o] = base[(size_t)o * ld + off + f];
    }
  }
  __syncthreads();
  if (z < 3) {
    float cacc[16] = {};
#pragma unroll 4
    for (int f = 0; f < FIN; ++f) {
      float x = xS[n][f];
      fx4 w0 = *(const fx4*)&wT[f][og * 16 + 0];
      fx4 w1 = *(const fx4*)&wT[f][og * 16 + 4];
      fx4 w2 = *(const fx4*)&wT[f][og * 16 + 8];
      fx4 w3 = *(const fx4*)&wT[f][og * 16 + 12];
#pragma unroll
      for (int k = 0; k < 4; ++k) {
        cacc[k + 0]  = fmaf(w0[k], x, cacc[k + 0]);
        cacc[k + 4]  = fmaf(w1[k], x, cacc[k + 4]);
        cacc[k + 8]  = fmaf(w2[k], x, cacc[k + 8]);
        cacc[k + 12] = fmaf(w3[k], x, cacc[k + 12]);
      }
    }
#pragma unroll
    for (int k = 0; k < 16; ++k)
      T[(((size_t)b * 3 + z) * 64 + og * 16 + k) * N + n0 + n] = cacc[k];
  } else {
    float cacc[4] = {};
#pragma unroll 4
    for (int f = 0; f < FIN; ++f) {
      float x = xS[n][f];
      fx4 w0 = *(const fx4*)&wT[f][og * 4];
#pragma unroll
      for (int k = 0; k < 4; ++k) cacc[k] = fmaf(w0[k], x, cacc[k]);
    }
#pragma unroll
    for (int k = 0; k < 4; ++k)
      projb[((size_t)b * DK + og * 4 + k) * N + n0 + n] = cacc[k];
  }
}

// ---------------- adjacency+deg+PV via bf16 MFMA; fragments direct from global ----------------
__global__ __launch_bounds__(256, 4) void k_adjmsg(const float* __restrict__ proj,
                                                   const float* __restrict__ T,
                                                   float* __restrict__ pdmsg,  // (nch,B,F,N)
                                                   float* __restrict__ pdeg,   // (nch,B,N)
                                                   int nch, int cpx) {
  const int NCb = N / nch;
  int i = blockIdx.x;
  int xcd = i & 7;
  int j = i >> 3;
  int lc = j / MT;
  int mtile = j - lc * MT;
  int combo = xcd * cpx + lc;  // bijective XCD swizzle
  int ch = combo >> 2;
  int b  = combo & 3;
  int M0 = mtile * 64;
  int n0 = ch * NCb;

  int t = threadIdx.x;
  int w = t >> 6, l = t & 63;
  int l31 = l & 31, lh = l >> 5;
  int mq = w & 1, nq = w >> 1;
  int fq = w & 1, mq2 = w >> 1;

  const float* pb = proj + (size_t)b * DK * N;
  const float* vb = T + ((size_t)b * 3 + 1) * (size_t)F * N;  // W2·V slice

  __shared__ __align__(16) short adjT[64][68];
  __shared__ __align__(16) short vS[64][68];
  __shared__ float sqmS[64];
  __shared__ float degS[2][64];

  // ---- A-fragment + sqm direct from global (coalesced dword per d-row) ----
  bf16x8 afrag;
  {
    int am = l31 + 32 * mq;
    float sq = 0.f;
#pragma unroll
    for (int i2 = 0; i2 < 8; ++i2) {
      float xr;
      afrag[i2] = f2bf(pb[(size_t)(lh * 8 + i2) * N + M0 + am], &xr);
      sq = fmaf(xr, xr, sq);
    }
    sq += __shfl_xor(sq, 32);
    if (l < 32) sqmS[am] = sq;
  }
  __syncthreads();
  float sqmr[16];
#pragma unroll
  for (int r = 0; r < 16; ++r)
    sqmr[r] = sqmS[(r & 3) + 8 * (r >> 2) + 4 * lh + 32 * mq];

  f32x16 acc;
#pragma unroll
  for (int r = 0; r < 16; ++r) acc[r] = 0.f;
  float pdm[16];
#pragma unroll
  for (int r = 0; r < 16; ++r) pdm[r] = 0.f;

  for (int nt = 0; nt < NCb; nt += 64) {
    // ---- B-fragment + sqn direct from global (no LDS) ----
    bf16x8 bfrag;
    float sqn = 0.f;
    {
      int bn = l31 + 32 * nq;
#pragma unroll
      for (int i2 = 0; i2 < 8; ++i2) {
        float xr;
        bfrag[i2] = f2bf(pb[(size_t)(lh * 8 + i2) * N + n0 + nt + bn], &xr);
        sqn = fmaf(xr, xr, sqn);
      }
      sqn += __shfl_xor(sqn, 32);
    }
    __syncthreads();  // prev PV done reading vS/adjT
    {  // stage V (W2·V) as bf16
      int f = t >> 2, nb16 = (t & 3) * 16;
#pragma unroll
      for (int jj = 0; jj < 4; ++jj) {
        float4 v4 = *(const float4*)&vb[(size_t)f * N + n0 + nt + nb16 + 4 * jj];
        bf16x4 o;
        o[0] = f2bf(v4.x); o[1] = f2bf(v4.y); o[2] = f2bf(v4.z); o[3] = f2bf(v4.w);
        *(bf16x4*)&vS[f][nb16 + 4 * jj] = o;
      }
    }
    // ---- gram via MFMA + exp -> adjT ----
    f32x16 gz;
#pragma unroll
    for (int r = 0; r < 16; ++r) gz[r] = 0.f;
    f32x16 g = __builtin_amdgcn_mfma_f32_32x32x16_bf16(afrag, bfrag, gz, 0, 0, 0);
    int ncol = l31 + 32 * nq;
#pragma unroll
    for (int r = 0; r < 16; ++r) {
      int m = (r & 3) + 8 * (r >> 2) + 4 * lh + 32 * mq;
      float dist = fmaxf(sqmr[r] + sqn - 2.f * g[r], 0.f);
      float a = __expf(-dist);
      pdm[r] += a;
      adjT[m][ncol] = f2bf(a);
    }
    __syncthreads();
    // ---- PV via MFMA: acc[f][m] += sum_n V[f][n] * adj[m][n] ----
#pragma unroll
    for (int kk = 0; kk < 4; ++kk) {
      int nb = kk * 16 + lh * 8;
      int fA = l31 + 32 * fq;
      int mB = l31 + 32 * mq2;
      bf16x4 alo = *(const bf16x4*)&vS[fA][nb];
      bf16x4 ahi = *(const bf16x4*)&vS[fA][nb + 4];
      bf16x4 blo = *(const bf16x4*)&adjT[mB][nb];
      bf16x4 bhi = *(const bf16x4*)&adjT[mB][nb + 4];
      bf16x8 af2, bf2;
#pragma unroll
      for (int i2 = 0; i2 < 4; ++i2) {
        af2[i2] = alo[i2]; af2[i2 + 4] = ahi[i2];
        bf2[i2] = blo[i2]; bf2[i2 + 4] = bhi[i2];
      }
      acc = __builtin_amdgcn_mfma_f32_32x32x16_bf16(af2, bf2, acc, 0, 0, 0);
    }
  }
#pragma unroll
  for (int r = 0; r < 16; ++r) {
    pdm[r] += __shfl_xor(pdm[r], 1);
    pdm[r] += __shfl_xor(pdm[r], 2);
    pdm[r] += __shfl_xor(pdm[r], 4);
    pdm[r] += __shfl_xor(pdm[r], 8);
    pdm[r] += __shfl_xor(pdm[r], 16);
  }
  if (l31 == 0) {
#pragma unroll
    for (int r = 0; r < 16; ++r)
      degS[nq][(r & 3) + 8 * (r >> 2) + 4 * lh + 32 * mq] = pdm[r];
  }
  __syncthreads();
  if (t < 64) {
    float s = degS[0][t] + degS[1][t];
    __builtin_nontemporal_store(s, &pdeg[(size_t)combo * N + M0 + t]);
  }
  float* pdm_g = pdmsg + (size_t)combo * F * N;
  int m_out = l31 + 32 * mq2;
#pragma unroll
  for (int r = 0; r < 16; ++r) {
    int f_r = (r & 3) + 8 * (r >> 2) + 4 * lh + 32 * fq;
    __builtin_nontemporal_store(acc[r], &pdm_g[(size_t)f_r * N + M0 + m_out]);
  }
}

// ---------------- fused chunk-combine + epilogue ----------------
template<int CH>
__global__ __launch_bounds__(256) void k_ep(const float* __restrict__ pdmsg,
                                            const float* __restrict__ pdeg,
                                            const float* __restrict__ T,
                                            const float* __restrict__ bias,
                                            const float* __restrict__ bres,
                                            float* __restrict__ out) {
  int idx = blockIdx.x * 256 + threadIdx.x;  // float4 units, total B*F*N/4
  int row = idx >> 9;                        // N/4 = 512
  int c4 = idx & 511;
  int o = row & 63, b = row >> 6;
  fx4 dm = {0.f, 0.f, 0.f, 0.f};
  fx4 dg = {0.f, 0.f, 0.f, 0.f};
#pragma unroll
  for (int c = 0; c < CH; ++c) {
    dm += __builtin_nontemporal_load(&((const fx4*)pdmsg)[(((size_t)c * B + b) * 64 + o) * 512 + c4]);
    dg += ((const fx4*)pdeg)[((size_t)c * B + b) * 512 + c4];
  }
  fx4 t0 = ((const fx4*)T)[(((size_t)b * 3 + 0) * 64 + o) * 512 + c4];
  fx4 t2 = ((const fx4*)T)[(((size_t)b * 3 + 2) * 64 + o) * 512 + c4];
  float bi = bias[o], br = bres[o];
  fx4 r = dm + t0 * dg;
  fx4 ov;
#pragma unroll
  for (int j = 0; j < 4; ++j) ov[j] = fmaxf(r[j] + bi, 0.f) + t2[j] + br;
  ((fx4*)out)[((size_t)b * 64 + o) * 512 + c4] = ov;
}

// ---------------- readout: pool + instance-norm + fcl + sigmoid ----------------
__global__ __launch_bounds__(256) void k_readout(const float* __restrict__ emb,
                                                 const float* __restrict__ fw,
                                                 const float* __restrict__ fb,
                                                 float* __restrict__ out) {
  int b = blockIdx.x, t = threadIdx.x, w = t >> 6, l = t & 63;
  __shared__ float red[64];
  for (int fr = w * 16; fr < w * 16 + 16; ++fr) {
    const fx4* p = (const fx4*)(emb + ((size_t)b * F + fr) * N);
    float s = 0.f;
#pragma unroll
    for (int i = l; i < N / 4; i += 64) {
      fx4 v = p[i];
      s += v.x + v.y + v.z + v.w;
    }
#pragma unroll
    for (int off = 1; off < 64; off <<= 1) s += __shfl_xor(s, off);
    if (l == 0) red[fr] = s;
  }
  __syncthreads();
  if (t == 0) {
    float pooled[64];
    float mn = 0.f;
    for (int q = 0; q < 64; ++q) {
      float po = red[q] / (float)N;
      pooled[q] = po;
      mn += po;
    }
    mn /= 64.f;
    float var = 0.f;
    for (int q = 0; q < 64; ++q) {
      float d2 = pooled[q] - mn;
      var = fmaf(d2, d2, var);
    }
    var /= 64.f;
    float r = rsqrtf(var + EPS);
    float lg = fb[0];
    for (int q = 0; q < 64; ++q) lg = fmaf((pooled[q] - mn) * r, fw[q], lg);
    out[b] = 1.f / (1.f + __expf(-lg));
  }
}

}  // namespace

extern "C" void kernel_launch(void* const* d_in, const int* in_sizes, int n_in,
                              void* d_out, int out_size, void* d_ws, size_t ws_size,
                              hipStream_t stream) {
  const float* emb_in   = (const float*)d_in[0];
  const float* sigma    = (const float*)d_in[1];
  const float* fst_w    = (const float*)d_in[2];
  const float* fst_b    = (const float*)d_in[3];
  const float* fst_wres = (const float*)d_in[4];
  const float* fst_bres = (const float*)d_in[5];
  const float* adj_proj = (const float*)d_in[6];
  const float* w        = (const float*)d_in[7];
  const float* bw       = (const float*)d_in[8];
  const float* wres     = (const float*)d_in[9];
  const float* bres     = (const float*)d_in[10];
  const float* fcl_w    = (const float*)d_in[11];
  const float* fcl_b    = (const float*)d_in[12];

  auto need_bytes = [](int nch) -> size_t {
    size_t f = 0;
    f += (size_t)nch * B * N;           // pdeg
    f += (size_t)nch * B * F * N;       // pdmsg
    f += 2 * (size_t)B * F * N;         // embA, embB
    f += (size_t)B * DK * N;            // projb
    f += 3 * (size_t)B * F * N;         // T
    f += 2 * (size_t)B * F;             // mean, rstd
    return f * 4;
  };
  int nch = (ws_size >= need_bytes(8)) ? 8 : 4;
  int cpx = nch * B / 8;

  float* ws = (float*)d_ws;
  float* pdeg  = ws;  ws += (size_t)nch * B * N;
  float* pdmsg = ws;  ws += (size_t)nch * B * F * N;
  float* embA  = ws;  ws += (size_t)B * F * N;
  float* embB  = ws;  ws += (size_t)B * F * N;
  float* projb = ws;  ws += (size_t)B * DK * N;
  float* T     = ws;  ws += 3 * (size_t)B * F * N;
  float* meanb = ws;  ws += (size_t)B * F;
  float* rstdb = ws;  ws += (size_t)B * F;

  constexpr int EPB = (B * F * N / 4) / 256;  // 512 blocks for k_ep

  // ---- layer 0 (sigma folded into scaled+padded proj; no spatialnorm) ----
  k_prep0<<<dim3((B * DK * N / 4 + 255) / 256), 256, 0, stream>>>(emb_in, sigma, projb);
  k_wx<F0, false><<<dim3(N / 64, B, 3), 256, 0, stream>>>(
      emb_in, nullptr, nullptr, fst_w, fst_wres, nullptr, T, projb);
  k_adjmsg<<<dim3(MT * nch * B), 256, 0, stream>>>(projb, T, pdmsg, pdeg, nch, cpx);
  if (nch == 8)
    k_ep<8><<<dim3(EPB), 256, 0, stream>>>(pdmsg, pdeg, T, fst_b, fst_bres, embA);
  else
    k_ep<4><<<dim3(EPB), 256, 0, stream>>>(pdmsg, pdeg, T, fst_b, fst_bres, embA);

  // ---- layers 1..2 (spatialnorm fused into k_wx via stats) ----
  const float* src = embA;
  float* dst = embB;
  for (int i = 0; i < 2; ++i) {
    k_stats<<<dim3(B * F), 256, 0, stream>>>(src, meanb, rstdb);
    k_wx<F, true><<<dim3(N / 64, B, 4), 256, 0, stream>>>(
        src, meanb, rstdb, w + (size_t)i * F * 2 * F, wres + (size_t)i * F * F,
        adj_proj + (size_t)i * DK * F, T, projb);
    k_adjmsg<<<dim3(MT * nch * B), 256, 0, stream>>>(projb, T, pdmsg, pdeg, nch, cpx);
    if (nch == 8)
      k_ep<8><<<dim3(EPB), 256, 0, stream>>>(pdmsg, pdeg, T, bw + (size_t)i * F,
                                             bres + (size_t)i * F, dst);
    else
      k_ep<4><<<dim3(EPB), 256, 0, stream>>>(pdmsg, pdeg, T, bw + (size_t)i * F,
                                             bres + (size_t)i * F, dst);
    float* tmp = (float*)src;
    src = dst;
    dst = tmp;
  }

  k_readout<<<dim3(B), 256, 0, stream>>>(src, fcl_w, fcl_b, (float*)d_out);
}

// Round 11
// 112.047 us; speedup vs baseline: 2.7509x; 1.1698x over previous
//
#include <hip/hip_runtime.h>
#include <hip/hip_bf16.h>
#include <math.h>

namespace {

constexpr int B  = 4;
constexpr int N  = 2048;
constexpr int F0 = 6;
constexpr int F  = 64;
constexpr int DK = 16;
constexpr float EPS = 1e-5f;
constexpr int MT   = N / 64;  // m-tiles

typedef float fx4 __attribute__((ext_vector_type(4)));
typedef __attribute__((ext_vector_type(8)))  short bf16x8;
typedef __attribute__((ext_vector_type(4)))  short bf16x4;
typedef __attribute__((ext_vector_type(16))) float f32x16;

__device__ inline short f2bf(float x, float* xr) {
  __hip_bfloat16 h = __float2bfloat16(x);
  *xr = __bfloat162float(h);
  short s; __builtin_memcpy(&s, &h, 2);
  return s;
}
__device__ inline short f2bf(float x) {
  __hip_bfloat16 h = __float2bfloat16(x);
  short s; __builtin_memcpy(&s, &h, 2);
  return s;
}

// ---------------- weight-folding GEMMs; spatialnorm from ep-partials; layer0 proj path ----------------
// z<3: T[z] = {W1,W2,Wres}·norm(X).  z==3 && Ap: proj = Ap·X (raw X).
// z==3 && !Ap (layer 0): proj0 = X/sigma zero-padded to DK rows.
template<int FIN, bool NORM>
__global__ __launch_bounds__(256) void k_wx(const float* __restrict__ X,     // (B,FIN,N)
                                            const float* __restrict__ sigma, // layer0 only
                                            const float* __restrict__ ssum,  // (2*B*F) ep partials
                                            const float* __restrict__ ssq,
                                            const float* __restrict__ Wc,    // (64,2*FIN)
                                            const float* __restrict__ Wr,    // (64,FIN)
                                            const float* __restrict__ Ap,    // (DK,FIN) or null
                                            float* __restrict__ T,           // (B,3,64,N)
                                            float* __restrict__ projb) {     // (B,DK,N)
  int z = blockIdx.z, b = blockIdx.y, n0 = blockIdx.x * 64;
  int t = threadIdx.x, n = t & 63, og = t >> 6;
  __shared__ float xS[64][FIN + 1];
  __shared__ __align__(16) float wT[FIN][68];
  __shared__ float mnS[64], rsS[64];
  for (int e = t; e < FIN * 64; e += 256) {
    int f = e >> 6, nn = e & 63;
    xS[nn][f] = X[((size_t)b * FIN + f) * N + n0 + nn];
  }
  if (!(z == 3 && Ap == nullptr)) {
    const float* base; int ld, off, OUT;
    if (z == 0)      { base = Wc; ld = 2 * FIN; off = 0;   OUT = 64; }
    else if (z == 1) { base = Wc; ld = 2 * FIN; off = FIN; OUT = 64; }
    else if (z == 2) { base = Wr; ld = FIN;     off = 0;   OUT = 64; }
    else             { base = Ap; ld = FIN;     off = 0;   OUT = DK; }
    for (int e = t; e < OUT * FIN; e += 256) {
      int o = e / FIN, f = e - o * FIN;
      wT[f][o] = base[(size_t)o * ld + off + f];
    }
  }
  if (NORM && z < 3 && t < 64) {  // mean/rstd from ep partial sums (2 halves per row)
    int row = b * FIN + t;
    float S = ssum[2 * row] + ssum[2 * row + 1];
    float Q = ssq[2 * row] + ssq[2 * row + 1];
    float mn = S / (float)N;
    mnS[t] = mn;
    rsS[t] = rsqrtf(Q / (float)N - mn * mn + EPS);
  }
  __syncthreads();
  if (z < 3) {
    float cacc[16] = {};
#pragma unroll 4
    for (int f = 0; f < FIN; ++f) {
      float x = xS[n][f];
      if (NORM) x = (x - mnS[f]) * rsS[f];
      fx4 w0 = *(const fx4*)&wT[f][og * 16 + 0];
      fx4 w1 = *(const fx4*)&wT[f][og * 16 + 4];
      fx4 w2 = *(const fx4*)&wT[f][og * 16 + 8];
      fx4 w3 = *(const fx4*)&wT[f][og * 16 + 12];
#pragma unroll
      for (int k = 0; k < 4; ++k) {
        cacc[k + 0]  = fmaf(w0[k], x, cacc[k + 0]);
        cacc[k + 4]  = fmaf(w1[k], x, cacc[k + 4]);
        cacc[k + 8]  = fmaf(w2[k], x, cacc[k + 8]);
        cacc[k + 12] = fmaf(w3[k], x, cacc[k + 12]);
      }
    }
#pragma unroll
    for (int k = 0; k < 16; ++k)
      T[(((size_t)b * 3 + z) * 64 + og * 16 + k) * N + n0 + n] = cacc[k];
  } else if (Ap != nullptr) {
    float cacc[4] = {};
#pragma unroll 4
    for (int f = 0; f < FIN; ++f) {
      float x = xS[n][f];
      fx4 w0 = *(const fx4*)&wT[f][og * 4];
#pragma unroll
      for (int k = 0; k < 4; ++k) cacc[k] = fmaf(w0[k], x, cacc[k]);
    }
#pragma unroll
    for (int k = 0; k < 4; ++k)
      projb[((size_t)b * DK + og * 4 + k) * N + n0 + n] = cacc[k];
  } else {  // layer-0 proj: scaled + zero-padded
    float inv = 1.f / sigma[0];
#pragma unroll
    for (int k = 0; k < 4; ++k) {
      int d = og * 4 + k;
      float v = (d < F0) ? xS[n][d] * inv : 0.f;
      projb[((size_t)b * DK + d) * N + n0 + n] = v;
    }
  }
}

// ---------------- adjacency+deg+PV via bf16 MFMA; double-buffered LDS, 1 barrier/iter ----------------
__global__ __launch_bounds__(256, 4) void k_adjmsg(const float* __restrict__ proj,
                                                   const float* __restrict__ T,
                                                   float* __restrict__ pdmsg,  // (nch,B,F,N)
                                                   float* __restrict__ pdeg,   // (nch,B,N)
                                                   int nch, int cpx) {
  const int NCb = N / nch;
  int i = blockIdx.x;
  int xcd = i & 7;
  int j = i >> 3;
  int lc = j / MT;
  int mtile = j - lc * MT;
  int combo = xcd * cpx + lc;  // bijective XCD swizzle
  int ch = combo >> 2;
  int b  = combo & 3;
  int M0 = mtile * 64;
  int n0 = ch * NCb;

  int t = threadIdx.x;
  int w = t >> 6, l = t & 63;
  int l31 = l & 31, lh = l >> 5;
  int mq = w & 1, nq = w >> 1;
  int fq = w & 1, mq2 = w >> 1;

  const float* pb = proj + (size_t)b * DK * N;
  const float* vb = T + ((size_t)b * 3 + 1) * (size_t)F * N;  // W2·V slice

  __shared__ __align__(16) short adjT[2][64][68];
  __shared__ __align__(16) short vS[2][64][68];
  __shared__ float sqmS[64];
  __shared__ float degS[2][64];

  // ---- A-fragment + sqm direct from global ----
  bf16x8 afrag;
  {
    int am = l31 + 32 * mq;
    float sq = 0.f;
#pragma unroll
    for (int i2 = 0; i2 < 8; ++i2) {
      float xr;
      afrag[i2] = f2bf(pb[(size_t)(lh * 8 + i2) * N + M0 + am], &xr);
      sq = fmaf(xr, xr, sq);
    }
    sq += __shfl_xor(sq, 32);
    if (l < 32) sqmS[am] = sq;
  }
  __syncthreads();
  float sqmr[16];
#pragma unroll
  for (int r = 0; r < 16; ++r)
    sqmr[r] = sqmS[(r & 3) + 8 * (r >> 2) + 4 * lh + 32 * mq];

  f32x16 acc;
#pragma unroll
  for (int r = 0; r < 16; ++r) acc[r] = 0.f;
  float pdm[16];
#pragma unroll
  for (int r = 0; r < 16; ++r) pdm[r] = 0.f;

  int buf = 0;
  for (int nt = 0; nt < NCb; nt += 64) {
    // B-fragment + sqn direct from global
    bf16x8 bfrag;
    float sqn = 0.f;
    {
      int bn = l31 + 32 * nq;
#pragma unroll
      for (int i2 = 0; i2 < 8; ++i2) {
        float xr;
        bfrag[i2] = f2bf(pb[(size_t)(lh * 8 + i2) * N + n0 + nt + bn], &xr);
        sqn = fmaf(xr, xr, sqn);
      }
      sqn += __shfl_xor(sqn, 32);
    }
    {  // stage V (W2·V) as bf16 into buf
      int f = t >> 2, nb16 = (t & 3) * 16;
#pragma unroll
      for (int jj = 0; jj < 4; ++jj) {
        float4 v4 = *(const float4*)&vb[(size_t)f * N + n0 + nt + nb16 + 4 * jj];
        bf16x4 o;
        o[0] = f2bf(v4.x); o[1] = f2bf(v4.y); o[2] = f2bf(v4.z); o[3] = f2bf(v4.w);
        *(bf16x4*)&vS[buf][f][nb16 + 4 * jj] = o;
      }
    }
    // gram via MFMA + exp -> adjT[buf]
    f32x16 gz;
#pragma unroll
    for (int r = 0; r < 16; ++r) gz[r] = 0.f;
    f32x16 g = __builtin_amdgcn_mfma_f32_32x32x16_bf16(afrag, bfrag, gz, 0, 0, 0);
    int ncol = l31 + 32 * nq;
#pragma unroll
    for (int r = 0; r < 16; ++r) {
      int m = (r & 3) + 8 * (r >> 2) + 4 * lh + 32 * mq;
      float dist = fmaxf(sqmr[r] + sqn - 2.f * g[r], 0.f);
      float a = __expf(-dist);
      pdm[r] += a;
      adjT[buf][m][ncol] = f2bf(a);
    }
    __syncthreads();  // adjT[buf]/vS[buf] ready; prev buffer free for next iter
    // PV via MFMA: acc[f][m] += sum_n V[f][n] * adj[m][n]
#pragma unroll
    for (int kk = 0; kk < 4; ++kk) {
      int nb = kk * 16 + lh * 8;
      int fA = l31 + 32 * fq;
      int mB = l31 + 32 * mq2;
      bf16x4 alo = *(const bf16x4*)&vS[buf][fA][nb];
      bf16x4 ahi = *(const bf16x4*)&vS[buf][fA][nb + 4];
      bf16x4 blo = *(const bf16x4*)&adjT[buf][mB][nb];
      bf16x4 bhi = *(const bf16x4*)&adjT[buf][mB][nb + 4];
      bf16x8 af2, bf2;
#pragma unroll
      for (int i2 = 0; i2 < 4; ++i2) {
        af2[i2] = alo[i2]; af2[i2 + 4] = ahi[i2];
        bf2[i2] = blo[i2]; bf2[i2 + 4] = bhi[i2];
      }
      acc = __builtin_amdgcn_mfma_f32_32x32x16_bf16(af2, bf2, acc, 0, 0, 0);
    }
    buf ^= 1;
  }
#pragma unroll
  for (int r = 0; r < 16; ++r) {
    pdm[r] += __shfl_xor(pdm[r], 1);
    pdm[r] += __shfl_xor(pdm[r], 2);
    pdm[r] += __shfl_xor(pdm[r], 4);
    pdm[r] += __shfl_xor(pdm[r], 8);
    pdm[r] += __shfl_xor(pdm[r], 16);
  }
  if (l31 == 0) {
#pragma unroll
    for (int r = 0; r < 16; ++r)
      degS[nq][(r & 3) + 8 * (r >> 2) + 4 * lh + 32 * mq] = pdm[r];
  }
  __syncthreads();
  if (t < 64) {
    float s = degS[0][t] + degS[1][t];
    __builtin_nontemporal_store(s, &pdeg[(size_t)combo * N + M0 + t]);
  }
  float* pdm_g = pdmsg + (size_t)combo * F * N;
  int m_out = l31 + 32 * mq2;
#pragma unroll
  for (int r = 0; r < 16; ++r) {
    int f_r = (r & 3) + 8 * (r >> 2) + 4 * lh + 32 * fq;
    __builtin_nontemporal_store(acc[r], &pdm_g[(size_t)f_r * N + M0 + m_out]);
  }
}

// ---------------- fused chunk-combine + epilogue + row-stat partials ----------------
// Block = half an output row; emits (sum, sumsq) partials for next layer's spatialnorm
// and the readout's node-pool.
template<int CH>
__global__ __launch_bounds__(256) void k_ep(const float* __restrict__ pdmsg,
                                            const float* __restrict__ pdeg,
                                            const float* __restrict__ T,
                                            const float* __restrict__ bias,
                                            const float* __restrict__ bres,
                                            float* __restrict__ out,
                                            float* __restrict__ ssum,   // (2*B*F)
                                            float* __restrict__ ssq) {  // (2*B*F)
  int t = threadIdx.x;
  int idx = blockIdx.x * 256 + t;  // fx4 units, total B*F*N/4
  int row = idx >> 9;              // N/4 = 512
  int c4 = idx & 511;
  int o = row & 63, b = row >> 6;
  fx4 dm = {0.f, 0.f, 0.f, 0.f};
  fx4 dg = {0.f, 0.f, 0.f, 0.f};
#pragma unroll
  for (int c = 0; c < CH; ++c) {
    dm += __builtin_nontemporal_load(&((const fx4*)pdmsg)[(((size_t)c * B + b) * 64 + o) * 512 + c4]);
    dg += ((const fx4*)pdeg)[((size_t)c * B + b) * 512 + c4];
  }
  fx4 t0 = ((const fx4*)T)[(((size_t)b * 3 + 0) * 64 + o) * 512 + c4];
  fx4 t2 = ((const fx4*)T)[(((size_t)b * 3 + 2) * 64 + o) * 512 + c4];
  float bi = bias[o], br = bres[o];
  fx4 r = dm + t0 * dg;
  fx4 ov;
#pragma unroll
  for (int j = 0; j < 4; ++j) ov[j] = fmaxf(r[j] + bi, 0.f) + t2[j] + br;
  ((fx4*)out)[((size_t)b * 64 + o) * 512 + c4] = ov;
  // partial (sum, sumsq) for this half-row
  float ps = ov[0] + ov[1] + ov[2] + ov[3];
  float pq = fmaf(ov[0], ov[0], fmaf(ov[1], ov[1], fmaf(ov[2], ov[2], ov[3] * ov[3])));
#pragma unroll
  for (int off = 1; off < 64; off <<= 1) {
    ps += __shfl_xor(ps, off);
    pq += __shfl_xor(pq, off);
  }
  __shared__ float r1[4], r2[4];
  if ((t & 63) == 0) { r1[t >> 6] = ps; r2[t >> 6] = pq; }
  __syncthreads();
  if (t == 0) {
    ssum[blockIdx.x] = r1[0] + r1[1] + r1[2] + r1[3];
    ssq[blockIdx.x]  = r2[0] + r2[1] + r2[2] + r2[3];
  }
}

// ---------------- readout from ep partials: pool + instance-norm + fcl + sigmoid ----------------
__global__ __launch_bounds__(256) void k_readout(const float* __restrict__ ssum,
                                                 const float* __restrict__ fw,
                                                 const float* __restrict__ fb,
                                                 float* __restrict__ out) {
  int t = threadIdx.x, b = t >> 6, l = t & 63;
  int row = b * 64 + l;
  float po = (ssum[2 * row] + ssum[2 * row + 1]) / (float)N;
  float mn = po;
#pragma unroll
  for (int off = 1; off < 64; off <<= 1) mn += __shfl_xor(mn, off);
  mn *= (1.f / 64.f);
  float d = po - mn;
  float var = d * d;
#pragma unroll
  for (int off = 1; off < 64; off <<= 1) var += __shfl_xor(var, off);
  var *= (1.f / 64.f);
  float rs = rsqrtf(var + EPS);
  float lg = d * rs * fw[l];
#pragma unroll
  for (int off = 1; off < 64; off <<= 1) lg += __shfl_xor(lg, off);
  if (l == 0) out[b] = 1.f / (1.f + __expf(-(lg + fb[0])));
}

}  // namespace

extern "C" void kernel_launch(void* const* d_in, const int* in_sizes, int n_in,
                              void* d_out, int out_size, void* d_ws, size_t ws_size,
                              hipStream_t stream) {
  const float* emb_in   = (const float*)d_in[0];
  const float* sigma    = (const float*)d_in[1];
  const float* fst_w    = (const float*)d_in[2];
  const float* fst_b    = (const float*)d_in[3];
  const float* fst_wres = (const float*)d_in[4];
  const float* fst_bres = (const float*)d_in[5];
  const float* adj_proj = (const float*)d_in[6];
  const float* w        = (const float*)d_in[7];
  const float* bw       = (const float*)d_in[8];
  const float* wres     = (const float*)d_in[9];
  const float* bres     = (const float*)d_in[10];
  const float* fcl_w    = (const float*)d_in[11];
  const float* fcl_b    = (const float*)d_in[12];

  auto need_bytes = [](int nch) -> size_t {
    size_t f = 0;
    f += (size_t)nch * B * N;           // pdeg
    f += (size_t)nch * B * F * N;       // pdmsg
    f += 2 * (size_t)B * F * N;         // embA, embB
    f += (size_t)B * DK * N;            // projb
    f += 3 * (size_t)B * F * N;         // T
    f += 4 * (size_t)B * F;             // ssum, ssq
    return f * 4;
  };
  int nch = (ws_size >= need_bytes(8)) ? 8 : 4;
  int cpx = nch * B / 8;

  float* ws = (float*)d_ws;
  float* pdeg  = ws;  ws += (size_t)nch * B * N;
  float* pdmsg = ws;  ws += (size_t)nch * B * F * N;
  float* embA  = ws;  ws += (size_t)B * F * N;
  float* embB  = ws;  ws += (size_t)B * F * N;
  float* projb = ws;  ws += (size_t)B * DK * N;
  float* T     = ws;  ws += 3 * (size_t)B * F * N;
  float* ssum  = ws;  ws += 2 * (size_t)B * F;
  float* ssq   = ws;  ws += 2 * (size_t)B * F;

  constexpr int EPB = (B * F * N / 4) / 256;  // 512 blocks; block = half output row

  // ---- layer 0 (sigma folded; proj0 produced by z==3 path) ----
  k_wx<F0, false><<<dim3(N / 64, B, 4), 256, 0, stream>>>(
      emb_in, sigma, nullptr, nullptr, fst_w, fst_wres, nullptr, T, projb);
  k_adjmsg<<<dim3(MT * nch * B), 256, 0, stream>>>(projb, T, pdmsg, pdeg, nch, cpx);
  if (nch == 8)
    k_ep<8><<<dim3(EPB), 256, 0, stream>>>(pdmsg, pdeg, T, fst_b, fst_bres, embA, ssum, ssq);
  else
    k_ep<4><<<dim3(EPB), 256, 0, stream>>>(pdmsg, pdeg, T, fst_b, fst_bres, embA, ssum, ssq);

  // ---- layers 1..2 (spatialnorm from ep partials, fused into k_wx) ----
  const float* src = embA;
  float* dst = embB;
  for (int i = 0; i < 2; ++i) {
    k_wx<F, true><<<dim3(N / 64, B, 4), 256, 0, stream>>>(
        src, nullptr, ssum, ssq, w + (size_t)i * F * 2 * F, wres + (size_t)i * F * F,
        adj_proj + (size_t)i * DK * F, T, projb);
    k_adjmsg<<<dim3(MT * nch * B), 256, 0, stream>>>(projb, T, pdmsg, pdeg, nch, cpx);
    if (nch == 8)
      k_ep<8><<<dim3(EPB), 256, 0, stream>>>(pdmsg, pdeg, T, bw + (size_t)i * F,
                                             bres + (size_t)i * F, dst, ssum, ssq);
    else
      k_ep<4><<<dim3(EPB), 256, 0, stream>>>(pdmsg, pdeg, T, bw + (size_t)i * F,
                                             bres + (size_t)i * F, dst, ssum, ssq);
    float* tmp = (float*)src;
    src = dst;
    dst = tmp;
  }

  k_readout<<<dim3(1), 256, 0, stream>>>(ssum, fcl_w, fcl_b, (float*)d_out);
}

// Round 12
// 106.574 us; speedup vs baseline: 2.8921x; 1.0514x over previous
//
#include <hip/hip_runtime.h>
#include <hip/hip_bf16.h>
#include <math.h>

namespace {

constexpr int B  = 4;
constexpr int N  = 2048;
constexpr int F0 = 6;
constexpr int F  = 64;
constexpr int DK = 16;
constexpr float EPS = 1e-5f;
constexpr int MT   = N / 64;  // m-tiles

typedef float fx4 __attribute__((ext_vector_type(4)));
typedef __attribute__((ext_vector_type(8)))  short bf16x8;
typedef __attribute__((ext_vector_type(4)))  short bf16x4;
typedef __attribute__((ext_vector_type(16))) float f32x16;

__device__ inline short f2bf(float x, float* xr) {
  __hip_bfloat16 h = __float2bfloat16(x);
  *xr = __bfloat162float(h);
  short s; __builtin_memcpy(&s, &h, 2);
  return s;
}
__device__ inline short f2bf(float x) {
  __hip_bfloat16 h = __float2bfloat16(x);
  short s; __builtin_memcpy(&s, &h, 2);
  return s;
}

// ---------------- weight-folding GEMMs -> bf16 operands for adjmsg ----------------
// z==0: T slice0 = W1·norm(X) (fp32)   z==1: Tbf = bf16(W2·norm(X))
// z==2: T slice1 = Wres·norm(X) (fp32) z==3: projbf = bf16(Ap·X) + sqnb (rounded-val norms)
//        (layer 0: projbf = bf16(X/sigma) zero-padded to DK rows)
template<int FIN, bool NORM>
__global__ __launch_bounds__(256) void k_wx(const float* __restrict__ X,     // (B,FIN,N)
                                            const float* __restrict__ sigma, // layer0 only
                                            const float* __restrict__ ssum,  // (2*B*F) ep partials
                                            const float* __restrict__ ssq,
                                            const float* __restrict__ Wc,    // (64,2*FIN)
                                            const float* __restrict__ Wr,    // (64,FIN)
                                            const float* __restrict__ Ap,    // (DK,FIN) or null
                                            float* __restrict__ T,           // (B,2,64,N)
                                            short* __restrict__ Tbf,         // (B,64,N) bf16
                                            short* __restrict__ projbf,      // (B,DK,N) bf16
                                            float* __restrict__ sqnb) {      // (B,N)
  int z = blockIdx.z, b = blockIdx.y, n0 = blockIdx.x * 64;
  int t = threadIdx.x, n = t & 63, og = t >> 6;
  __shared__ float xS[64][FIN + 1];
  __shared__ __align__(16) float wT[FIN][68];
  __shared__ float mnS[64], rsS[64];
  __shared__ float sp[4][64];
  for (int e = t; e < FIN * 64; e += 256) {
    int f = e >> 6, nn = e & 63;
    xS[nn][f] = X[((size_t)b * FIN + f) * N + n0 + nn];
  }
  bool l0proj = (z == 3 && Ap == nullptr);
  if (!l0proj) {
    const float* base; int ld, off, OUT;
    if (z == 0)      { base = Wc; ld = 2 * FIN; off = 0;   OUT = 64; }
    else if (z == 1) { base = Wc; ld = 2 * FIN; off = FIN; OUT = 64; }
    else if (z == 2) { base = Wr; ld = FIN;     off = 0;   OUT = 64; }
    else             { base = Ap; ld = FIN;     off = 0;   OUT = DK; }
    for (int e = t; e < OUT * FIN; e += 256) {
      int o = e / FIN, f = e - o * FIN;
      wT[f][o] = base[(size_t)o * ld + off + f];
    }
  }
  if (NORM && z < 3 && t < 64) {  // mean/rstd from ep partial sums (2 halves/row)
    int row = b * FIN + t;
    float S = ssum[2 * row] + ssum[2 * row + 1];
    float Q = ssq[2 * row] + ssq[2 * row + 1];
    float mn = S / (float)N;
    mnS[t] = mn;
    rsS[t] = rsqrtf(Q / (float)N - mn * mn + EPS);
  }
  __syncthreads();
  if (z < 3) {
    float cacc[16] = {};
#pragma unroll 4
    for (int f = 0; f < FIN; ++f) {
      float x = xS[n][f];
      if (NORM) x = (x - mnS[f]) * rsS[f];
      fx4 w0 = *(const fx4*)&wT[f][og * 16 + 0];
      fx4 w1 = *(const fx4*)&wT[f][og * 16 + 4];
      fx4 w2 = *(const fx4*)&wT[f][og * 16 + 8];
      fx4 w3 = *(const fx4*)&wT[f][og * 16 + 12];
#pragma unroll
      for (int k = 0; k < 4; ++k) {
        cacc[k + 0]  = fmaf(w0[k], x, cacc[k + 0]);
        cacc[k + 4]  = fmaf(w1[k], x, cacc[k + 4]);
        cacc[k + 8]  = fmaf(w2[k], x, cacc[k + 8]);
        cacc[k + 12] = fmaf(w3[k], x, cacc[k + 12]);
      }
    }
    if (z == 1) {
#pragma unroll
      for (int k = 0; k < 16; ++k)
        Tbf[((size_t)b * 64 + og * 16 + k) * N + n0 + n] = f2bf(cacc[k]);
    } else {
      int sl = (z == 0) ? 0 : 1;
#pragma unroll
      for (int k = 0; k < 16; ++k)
        T[(((size_t)b * 2 + sl) * 64 + og * 16 + k) * N + n0 + n] = cacc[k];
    }
  } else {
    // proj path: compute 4 rows (d = og*4+k), round to bf16, write + sqnorm of rounded
    float r[4];
    if (Ap != nullptr) {
      float cacc[4] = {};
#pragma unroll 4
      for (int f = 0; f < FIN; ++f) {
        float x = xS[n][f];
        fx4 w0 = *(const fx4*)&wT[f][og * 4];
#pragma unroll
        for (int k = 0; k < 4; ++k) cacc[k] = fmaf(w0[k], x, cacc[k]);
      }
#pragma unroll
      for (int k = 0; k < 4; ++k) {
        short hs = f2bf(cacc[k], &r[k]);
        projbf[((size_t)b * DK + og * 4 + k) * N + n0 + n] = hs;
      }
    } else {  // layer 0: scaled + zero-padded
      float inv = 1.f / sigma[0];
#pragma unroll
      for (int k = 0; k < 4; ++k) {
        int d = og * 4 + k;
        float v = (d < F0) ? xS[n][d] * inv : 0.f;
        short hs = f2bf(v, &r[k]);
        projbf[((size_t)b * DK + d) * N + n0 + n] = hs;
      }
    }
    float s = 0.f;
#pragma unroll
    for (int k = 0; k < 4; ++k) s = fmaf(r[k], r[k], s);
    sp[og][n] = s;
    __syncthreads();
    if (t < 64) sqnb[(size_t)b * N + n0 + t] = sp[0][t] + sp[1][t] + sp[2][t] + sp[3][t];
  }
}

// ---------------- adjacency+deg+PV via bf16 MFMA; bf16 operands, precomputed norms ----------------
__global__ __launch_bounds__(256, 4) void k_adjmsg(const short* __restrict__ projbf,
                                                   const float* __restrict__ sqnb,
                                                   const short* __restrict__ Tbf,
                                                   float* __restrict__ pdmsg,  // (nch,B,F,N)
                                                   float* __restrict__ pdeg,   // (nch,B,N)
                                                   int nch, int cpx) {
  const int NCb = N / nch;
  int i = blockIdx.x;
  int xcd = i & 7;
  int j = i >> 3;
  int lc = j / MT;
  int mtile = j - lc * MT;
  int combo = xcd * cpx + lc;  // bijective XCD swizzle
  int ch = combo >> 2;
  int b  = combo & 3;
  int M0 = mtile * 64;
  int n0 = ch * NCb;

  int t = threadIdx.x;
  int w = t >> 6, l = t & 63;
  int l31 = l & 31, lh = l >> 5;
  int mq = w & 1, nq = w >> 1;
  int fq = w & 1, mq2 = w >> 1;

  const short* pb = projbf + (size_t)b * DK * N;
  const short* vb = Tbf + (size_t)b * F * N;   // bf16 W2·V
  const float* sq = sqnb + (size_t)b * N;

  __shared__ __align__(16) short adjT[2][64][68];
  __shared__ __align__(16) short vS[2][64][68];
  __shared__ float sqmS[64];
  __shared__ float degS[2][64];

  // A-fragment: direct bf16 loads (no cvt); sqm staged from precomputed norms
  bf16x8 afrag;
  {
    int am = l31 + 32 * mq;
#pragma unroll
    for (int i2 = 0; i2 < 8; ++i2)
      afrag[i2] = pb[(size_t)(lh * 8 + i2) * N + M0 + am];
  }
  if (t < 64) sqmS[t] = sq[M0 + t];
  __syncthreads();
  float sqmr[16];
#pragma unroll
  for (int r = 0; r < 16; ++r)
    sqmr[r] = sqmS[(r & 3) + 8 * (r >> 2) + 4 * lh + 32 * mq];

  f32x16 acc;
#pragma unroll
  for (int r = 0; r < 16; ++r) acc[r] = 0.f;
  float pdm[16];
#pragma unroll
  for (int r = 0; r < 16; ++r) pdm[r] = 0.f;

  int buf = 0;
  for (int nt = 0; nt < NCb; nt += 64) {
    // B-fragment + its node-norm, direct from global
    bf16x8 bfrag;
    int bn = l31 + 32 * nq;
#pragma unroll
    for (int i2 = 0; i2 < 8; ++i2)
      bfrag[i2] = pb[(size_t)(lh * 8 + i2) * N + n0 + nt + bn];
    float sqn_v = sq[n0 + nt + bn];
    {  // stage V: raw bf16 copy (no cvt), 32B/thread
      int f = t >> 2, nb16 = (t & 3) * 16;
#pragma unroll
      for (int jj = 0; jj < 4; ++jj) {
        *(bf16x4*)&vS[buf][f][nb16 + 4 * jj] =
            *(const bf16x4*)&vb[(size_t)f * N + n0 + nt + nb16 + 4 * jj];
      }
    }
    // gram via MFMA + exp -> adjT[buf]
    f32x16 gz;
#pragma unroll
    for (int r = 0; r < 16; ++r) gz[r] = 0.f;
    f32x16 g = __builtin_amdgcn_mfma_f32_32x32x16_bf16(afrag, bfrag, gz, 0, 0, 0);
#pragma unroll
    for (int r = 0; r < 16; ++r) {
      int m = (r & 3) + 8 * (r >> 2) + 4 * lh + 32 * mq;
      float dist = fmaxf(sqmr[r] + sqn_v - 2.f * g[r], 0.f);
      float a = __expf(-dist);
      pdm[r] += a;
      adjT[buf][m][bn] = f2bf(a);
    }
    __syncthreads();  // adjT[buf]/vS[buf] ready
    // PV via MFMA: acc[f][m] += sum_n V[f][n] * adj[m][n]
#pragma unroll
    for (int kk = 0; kk < 4; ++kk) {
      int nb = kk * 16 + lh * 8;
      int fA = l31 + 32 * fq;
      int mB = l31 + 32 * mq2;
      bf16x4 alo = *(const bf16x4*)&vS[buf][fA][nb];
      bf16x4 ahi = *(const bf16x4*)&vS[buf][fA][nb + 4];
      bf16x4 blo = *(const bf16x4*)&adjT[buf][mB][nb];
      bf16x4 bhi = *(const bf16x4*)&adjT[buf][mB][nb + 4];
      bf16x8 af2, bf2;
#pragma unroll
      for (int i2 = 0; i2 < 4; ++i2) {
        af2[i2] = alo[i2]; af2[i2 + 4] = ahi[i2];
        bf2[i2] = blo[i2]; bf2[i2 + 4] = bhi[i2];
      }
      acc = __builtin_amdgcn_mfma_f32_32x32x16_bf16(af2, bf2, acc, 0, 0, 0);
    }
    buf ^= 1;
  }
#pragma unroll
  for (int r = 0; r < 16; ++r) {
    pdm[r] += __shfl_xor(pdm[r], 1);
    pdm[r] += __shfl_xor(pdm[r], 2);
    pdm[r] += __shfl_xor(pdm[r], 4);
    pdm[r] += __shfl_xor(pdm[r], 8);
    pdm[r] += __shfl_xor(pdm[r], 16);
  }
  if (l31 == 0) {
#pragma unroll
    for (int r = 0; r < 16; ++r)
      degS[nq][(r & 3) + 8 * (r >> 2) + 4 * lh + 32 * mq] = pdm[r];
  }
  __syncthreads();
  if (t < 64) {
    float s = degS[0][t] + degS[1][t];
    __builtin_nontemporal_store(s, &pdeg[(size_t)combo * N + M0 + t]);
  }
  float* pdm_g = pdmsg + (size_t)combo * F * N;
  int m_out = l31 + 32 * mq2;
#pragma unroll
  for (int r = 0; r < 16; ++r) {
    int f_r = (r & 3) + 8 * (r >> 2) + 4 * lh + 32 * fq;
    __builtin_nontemporal_store(acc[r], &pdm_g[(size_t)f_r * N + M0 + m_out]);
  }
}

// ---------------- fused chunk-combine + epilogue + row-stat partials ----------------
template<int CH>
__global__ __launch_bounds__(256) void k_ep(const float* __restrict__ pdmsg,
                                            const float* __restrict__ pdeg,
                                            const float* __restrict__ T,   // (B,2,64,N)
                                            const float* __restrict__ bias,
                                            const float* __restrict__ bres,
                                            float* __restrict__ out,
                                            float* __restrict__ ssum,   // (2*B*F)
                                            float* __restrict__ ssq) {  // (2*B*F)
  int t = threadIdx.x;
  int idx = blockIdx.x * 256 + t;  // fx4 units, total B*F*N/4
  int row = idx >> 9;              // N/4 = 512
  int c4 = idx & 511;
  int o = row & 63, b = row >> 6;
  fx4 dm = {0.f, 0.f, 0.f, 0.f};
  fx4 dg = {0.f, 0.f, 0.f, 0.f};
#pragma unroll
  for (int c = 0; c < CH; ++c) {
    dm += __builtin_nontemporal_load(&((const fx4*)pdmsg)[(((size_t)c * B + b) * 64 + o) * 512 + c4]);
    dg += ((const fx4*)pdeg)[((size_t)c * B + b) * 512 + c4];
  }
  fx4 t0 = ((const fx4*)T)[(((size_t)b * 2 + 0) * 64 + o) * 512 + c4];
  fx4 t2 = ((const fx4*)T)[(((size_t)b * 2 + 1) * 64 + o) * 512 + c4];
  float bi = bias[o], br = bres[o];
  fx4 r = dm + t0 * dg;
  fx4 ov;
#pragma unroll
  for (int j = 0; j < 4; ++j) ov[j] = fmaxf(r[j] + bi, 0.f) + t2[j] + br;
  ((fx4*)out)[((size_t)b * 64 + o) * 512 + c4] = ov;
  float ps = ov[0] + ov[1] + ov[2] + ov[3];
  float pq = fmaf(ov[0], ov[0], fmaf(ov[1], ov[1], fmaf(ov[2], ov[2], ov[3] * ov[3])));
#pragma unroll
  for (int off = 1; off < 64; off <<= 1) {
    ps += __shfl_xor(ps, off);
    pq += __shfl_xor(pq, off);
  }
  __shared__ float r1[4], r2[4];
  if ((t & 63) == 0) { r1[t >> 6] = ps; r2[t >> 6] = pq; }
  __syncthreads();
  if (t == 0) {
    ssum[blockIdx.x] = r1[0] + r1[1] + r1[2] + r1[3];
    ssq[blockIdx.x]  = r2[0] + r2[1] + r2[2] + r2[3];
  }
}

// ---------------- readout from ep partials ----------------
__global__ __launch_bounds__(256) void k_readout(const float* __restrict__ ssum,
                                                 const float* __restrict__ fw,
                                                 const float* __restrict__ fb,
                                                 float* __restrict__ out) {
  int t = threadIdx.x, b = t >> 6, l = t & 63;
  int row = b * 64 + l;
  float po = (ssum[2 * row] + ssum[2 * row + 1]) / (float)N;
  float mn = po;
#pragma unroll
  for (int off = 1; off < 64; off <<= 1) mn += __shfl_xor(mn, off);
  mn *= (1.f / 64.f);
  float d = po - mn;
  float var = d * d;
#pragma unroll
  for (int off = 1; off < 64; off <<= 1) var += __shfl_xor(var, off);
  var *= (1.f / 64.f);
  float rs = rsqrtf(var + EPS);
  float lg = d * rs * fw[l];
#pragma unroll
  for (int off = 1; off < 64; off <<= 1) lg += __shfl_xor(lg, off);
  if (l == 0) out[b] = 1.f / (1.f + __expf(-(lg + fb[0])));
}

}  // namespace

extern "C" void kernel_launch(void* const* d_in, const int* in_sizes, int n_in,
                              void* d_out, int out_size, void* d_ws, size_t ws_size,
                              hipStream_t stream) {
  const float* emb_in   = (const float*)d_in[0];
  const float* sigma    = (const float*)d_in[1];
  const float* fst_w    = (const float*)d_in[2];
  const float* fst_b    = (const float*)d_in[3];
  const float* fst_wres = (const float*)d_in[4];
  const float* fst_bres = (const float*)d_in[5];
  const float* adj_proj = (const float*)d_in[6];
  const float* w        = (const float*)d_in[7];
  const float* bw       = (const float*)d_in[8];
  const float* wres     = (const float*)d_in[9];
  const float* bres     = (const float*)d_in[10];
  const float* fcl_w    = (const float*)d_in[11];
  const float* fcl_b    = (const float*)d_in[12];

  auto need_bytes = [](int nch) -> size_t {
    size_t f = 0;
    f += (size_t)nch * B * N;           // pdeg
    f += (size_t)nch * B * F * N;       // pdmsg
    f += 2 * (size_t)B * F * N;         // embA, embB
    f += 2 * (size_t)B * F * N;         // T (2 slices)
    f += (size_t)B * F * N / 2;         // Tbf (bf16)
    f += (size_t)B * DK * N / 2;        // projbf (bf16)
    f += (size_t)B * N;                 // sqnb
    f += 4 * (size_t)B * F;             // ssum, ssq
    return f * 4;
  };
  int nch = (ws_size >= need_bytes(8)) ? 8 : 4;
  int cpx = nch * B / 8;

  float* ws = (float*)d_ws;
  float* pdeg  = ws;  ws += (size_t)nch * B * N;
  float* pdmsg = ws;  ws += (size_t)nch * B * F * N;
  float* embA  = ws;  ws += (size_t)B * F * N;
  float* embB  = ws;  ws += (size_t)B * F * N;
  float* T     = ws;  ws += 2 * (size_t)B * F * N;
  short* Tbf   = (short*)ws;  ws += (size_t)B * F * N / 2;
  short* projbf = (short*)ws; ws += (size_t)B * DK * N / 2;
  float* sqnb  = ws;  ws += (size_t)B * N;
  float* ssum  = ws;  ws += 2 * (size_t)B * F;
  float* ssq   = ws;  ws += 2 * (size_t)B * F;

  constexpr int EPB = (B * F * N / 4) / 256;  // 512 blocks; block = half output row

  // ---- layer 0 ----
  k_wx<F0, false><<<dim3(N / 64, B, 4), 256, 0, stream>>>(
      emb_in, sigma, nullptr, nullptr, fst_w, fst_wres, nullptr, T, Tbf, projbf, sqnb);
  k_adjmsg<<<dim3(MT * nch * B), 256, 0, stream>>>(projbf, sqnb, Tbf, pdmsg, pdeg, nch, cpx);
  if (nch == 8)
    k_ep<8><<<dim3(EPB), 256, 0, stream>>>(pdmsg, pdeg, T, fst_b, fst_bres, embA, ssum, ssq);
  else
    k_ep<4><<<dim3(EPB), 256, 0, stream>>>(pdmsg, pdeg, T, fst_b, fst_bres, embA, ssum, ssq);

  // ---- layers 1..2 ----
  const float* src = embA;
  float* dst = embB;
  for (int i = 0; i < 2; ++i) {
    k_wx<F, true><<<dim3(N / 64, B, 4), 256, 0, stream>>>(
        src, nullptr, ssum, ssq, w + (size_t)i * F * 2 * F, wres + (size_t)i * F * F,
        adj_proj + (size_t)i * DK * F, T, Tbf, projbf, sqnb);
    k_adjmsg<<<dim3(MT * nch * B), 256, 0, stream>>>(projbf, sqnb, Tbf, pdmsg, pdeg, nch, cpx);
    if (nch == 8)
      k_ep<8><<<dim3(EPB), 256, 0, stream>>>(pdmsg, pdeg, T, bw + (size_t)i * F,
                                             bres + (size_t)i * F, dst, ssum, ssq);
    else
      k_ep<4><<<dim3(EPB), 256, 0, stream>>>(pdmsg, pdeg, T, bw + (size_t)i * F,
                                             bres + (size_t)i * F, dst, ssum, ssq);
    float* tmp = (float*)src;
    src = dst;
    dst = tmp;
  }

  k_readout<<<dim3(1), 256, 0, stream>>>(ssum, fcl_w, fcl_b, (float*)d_out);
}